// Round 5
// baseline (1604.675 us; speedup 1.0000x reference)
//
#include <hip/hip_runtime.h>
#include <stdint.h>
#include <stddef.h>

#define NN 25000     // nodes
#define NPAD 25008   // 1563*16
#define NBLK 1563    // node blocks of 16
#define NE 100000    // edges
#define FEAT 16
#define DD 64
#define NGG 512
#define NJ 1024
#define NS 2048
#define NO 105
#define SLOPE 0.01f
#define CTOT 4160    // 4096 A-columns + 64 bias columns
#define ASTRIDE 8352 // bytes per node row in LDS: 65 o-rows * 128B = 8320, pad to 8352 (16B aligned)

typedef short bf8 __attribute__((ext_vector_type(8)));   // 8 bf16 raw bits (4 VGPR)
typedef float f32x4 __attribute__((ext_vector_type(4)));

__device__ __forceinline__ float lk(float v){ return v > 0.f ? v : SLOPE*v; }
__device__ __forceinline__ unsigned short f2bf(float f){
  unsigned int x = __float_as_uint(f);
  x += 0x7fffu + ((x>>16)&1u);           // round-to-nearest-even
  return (unsigned short)(x>>16);
}
__device__ __forceinline__ float bf2f(unsigned short u){ return __uint_as_float(((unsigned int)u)<<16); }
__device__ __forceinline__ float sg(float x){ return 1.f/(1.f+expf(-x)); }
__device__ __forceinline__ unsigned fenc(float f){ unsigned u = __float_as_uint(f); return (u & 0x80000000u) ? ~u : (u | 0x80000000u); }
__device__ __forceinline__ float fdec(unsigned k){ unsigned u = (k & 0x80000000u) ? (k ^ 0x80000000u) : ~k; return __uint_as_float(u); }

// ---------- setup kernels ----------

// out = leaky(x @ lin0_w.T + lin0_b); also writes bf16 copy; zero-fills hbf pad rows
__global__ __launch_bounds__(256) void k_lin0(const float* __restrict__ x, const float* __restrict__ w,
                       const float* __restrict__ b, float* __restrict__ h, unsigned short* __restrict__ hbf){
  int wid = (blockIdx.x*blockDim.x + threadIdx.x) >> 6;
  int lane = threadIdx.x & 63;
  if (wid >= NPAD) return;
  if (wid >= NN){ hbf[(size_t)wid*DD + lane] = 0; return; }
  float xv = lane < FEAT ? x[wid*FEAT + lane] : 0.f;
  float acc = b[lane];
  #pragma unroll
  for (int f=0; f<FEAT; ++f) acc += __shfl(xv, f) * w[lane*FEAT + f];
  float v = lk(acc);
  h[wid*DD + lane] = v;
  hbf[(size_t)wid*DD + lane] = f2bf(v);
}

// w2x[c*64+i]: c<4096 -> bf16(net2_w flat[i*4096+c]) ; c=4096+o -> bf16(net2_b[i*64+o])
// (net2_w flat[i*4096 + o*64 + k] == net2_w[i*64+o][k], so c = o*64+k layout is exact)
__global__ __launch_bounds__(256) void k_w2x(const float* __restrict__ w2, const float* __restrict__ b2,
                                             unsigned short* __restrict__ o){
  int t = blockIdx.x*blockDim.x + threadIdx.x;
  if (t >= CTOT*DD) return;
  int c = t >> 6, i = t & 63;
  float v = (c < 4096) ? w2[(size_t)i*4096 + c] : b2[i*64 + (c - 4096)];
  o[t] = f2bf(v);
}

// generic transpose: T[c*R + r] = M[r*C + c]
__global__ __launch_bounds__(256) void k_tr(const float* __restrict__ m, float* __restrict__ t, int R, int C){
  int i = blockIdx.x*blockDim.x + threadIdx.x;
  if (i >= R*C) return;
  int r = i / C, c = i - r*C;
  t[c*R + r] = m[i];
}

__global__ __launch_bounds__(256) void k_deg(const int* __restrict__ dst, float* __restrict__ deg){
  int e = blockIdx.x*blockDim.x + threadIdx.x;
  if (e < NE) atomicAdd(&deg[dst[e]], 1.f);
}
__global__ __launch_bounds__(256) void k_invd(float* __restrict__ d){
  int n = blockIdx.x*blockDim.x + threadIdx.x;
  if (n < NN) d[n] = d[n] > 0.f ? 1.f/d[n] : 0.f;
}

// ---------- edge sort by src (counting sort) ----------
__global__ __launch_bounds__(256) void k_hist(const int* __restrict__ src, int* __restrict__ degS){
  int e = blockIdx.x*blockDim.x + threadIdx.x;
  if (e < NE) atomicAdd(&degS[src[e]], 1);
}
// single-block scan via wave shuffles: rowptr[0..NPAD]
__global__ __launch_bounds__(1024) void k_scan(const int* __restrict__ degS, int* __restrict__ rowptr){
  __shared__ int wsum[16];
  __shared__ int base;
  int tid = threadIdx.x, lane = tid & 63, wv = tid >> 6;
  if (tid == 0){ base = 0; rowptr[0] = 0; }
  __syncthreads();
  for (int c0 = 0; c0 < NPAD; c0 += 1024){
    int i = c0 + tid;
    int v = (i < NPAD) ? degS[i] : 0;
    int s = v;
    #pragma unroll
    for (int off=1; off<64; off<<=1){
      int t = __shfl_up(s, off);
      if (lane >= off) s += t;
    }
    if (lane == 63) wsum[wv] = s;
    __syncthreads();
    if (wv == 0 && lane < 16){
      int ws = wsum[lane];
      #pragma unroll
      for (int off=1; off<16; off<<=1){
        int t = __shfl_up(ws, off);
        if (lane >= off) ws += t;
      }
      wsum[lane] = ws;
    }
    __syncthreads();
    int wbase = (wv == 0) ? 0 : wsum[wv-1];
    if (i < NPAD) rowptr[i+1] = base + wbase + s;
    __syncthreads();
    if (tid == 0) base += wsum[15];
    __syncthreads();
  }
}
__global__ __launch_bounds__(256) void k_scatter(const int* __restrict__ src, const int* __restrict__ dst,
                         const int* __restrict__ rowptr, int* __restrict__ cnt,
                         int* __restrict__ sSrc, int* __restrict__ sDst, int* __restrict__ sEid){
  int e = blockIdx.x*blockDim.x + threadIdx.x;
  if (e >= NE) return;
  int s = src[e];
  int pos = rowptr[s] + atomicAdd(&cnt[s], 1);
  sSrc[pos] = s; sDst[pos] = dst[e]; sEid[pos] = e;
}
// e1 sorted: e1s[pos][k] = bf16(leaky(edge_attr[sEid[pos]] @ net1_w.T + net1_b))
__global__ __launch_bounds__(256) void k_e1s(const float* __restrict__ ea, const float* __restrict__ w,
                     const float* __restrict__ b, const int* __restrict__ sEid,
                     unsigned short* __restrict__ e1s){
  int t = blockIdx.x*blockDim.x + threadIdx.x;   // t = pos*64 + k
  if (t >= NE*DD) return;
  int pos = t >> 6, k = t & 63;
  int e = sEid[pos];
  float acc = b[k];
  #pragma unroll
  for (int a=0; a<4; ++a) acc += ea[e*4+a] * w[k*4+a];
  e1s[t] = f2bf(lk(acc));
}

// ---------- fused: per 16-node block, A-tile in LDS (swizzled), then MFMA edge-GEMMs ----------
// Phase A: A[n][c] = sum_i w2x[c][i]*hbf[n][i] (c = o*64+k; c=4096+o is bias), bf16 into LDS.
//   LDS addr for (n, c): o=c>>6, k=c&63, slot_lin=k>>3;
//   byte = n*ASTRIDE + o*128 + ((slot_lin ^ (o&7) ^ ((n&1)<<2))<<4) + (k&7)*2   [XOR swizzle, both sides]
// Phase B: wave wv owns node n0+wv; per 16-edge M-tile: MFMA( e1 rows, A64[o][k] cols ) + bias + atomic scatter.
__global__ __launch_bounds__(1024) void k_fused8(const unsigned short* __restrict__ w2x,
                                                const unsigned short* __restrict__ hbf,
                                                const unsigned short* __restrict__ e1s,
                                                const int* __restrict__ sDst,
                                                const int* __restrict__ rowptr,
                                                float* __restrict__ aggr){
  extern __shared__ char smem[];
  int lane = threadIdx.x & 63;
  int wv   = threadIdx.x >> 6;           // 0..15
  int n0   = blockIdx.x * 16;
  int r16 = lane & 15, kg = lane >> 4;

  // persistent B-fragments: bf16 h rows of the 16 nodes (col = node r16)
  const unsigned short* hp = hbf + (size_t)(n0 + r16)*DD;
  bf8 bh0 = *(const bf8*)(hp + kg*8);
  bf8 bh1 = *(const bf8*)(hp + 32 + kg*8);

  // phase A: 260 c-tiles round-robin over 16 waves; lane holds (n=r16, c=t*16+kg*4+j)
  {
    int slot_w0 = kg >> 1;               // (t&3)*2 added per-t
    int swzn = (r16 & 1) << 2;
    for (int t = wv; t < 260; t += 16){
      const unsigned short* wp = w2x + (size_t)t*1024 + r16*64;
      bf8 a0 = *(const bf8*)(wp + kg*8);
      bf8 a1 = *(const bf8*)(wp + 32 + kg*8);
      f32x4 acc = {0.f,0.f,0.f,0.f};
      acc = __builtin_amdgcn_mfma_f32_16x16x32_bf16(a0, bh0, acc, 0,0,0);
      acc = __builtin_amdgcn_mfma_f32_16x16x32_bf16(a1, bh1, acc, 0,0,0);
      unsigned u0 = (unsigned)f2bf(acc[0]) | ((unsigned)f2bf(acc[1]) << 16);
      unsigned u1 = (unsigned)f2bf(acc[2]) | ((unsigned)f2bf(acc[3]) << 16);
      unsigned long long ull = (unsigned long long)u0 | ((unsigned long long)u1 << 32);
      int o = t >> 2;
      int slot = (((t & 3) * 2 + slot_w0) ^ (o & 7) ^ swzn);
      *(unsigned long long*)(smem + (size_t)r16*ASTRIDE + o*128 + (slot<<4) + ((kg & 1) * 8)) = ull;
    }
  }
  __syncthreads();

  // phase B: wave wv = node n0+wv
  {
    int node = n0 + wv;
    int estart = rowptr[node], eend = rowptr[node + 1];
    const char* ab = smem + (size_t)wv*ASTRIDE;
    int swzn = (wv & 1) << 2;
    for (int eg = estart; eg < eend; eg += 16){
      // A-frags: edge rows (row = r16 -> edge eg+r16), zero-filled beyond degree
      bf8 af0 = {0,0,0,0,0,0,0,0}, af1 = {0,0,0,0,0,0,0,0};
      int er = eg + r16;
      if (er < eend){
        af0 = *(const bf8*)(e1s + (size_t)er*DD + kg*8);
        af1 = *(const bf8*)(e1s + (size_t)er*DD + 32 + kg*8);
      }
      // dst rows for this lane's 4 output edges (row = kg*4+j)
      int ebase = eg + kg*4;
      #pragma unroll
      for (int nt=0; nt<4; ++nt){
        int o = nt*16 + r16;
        int om7 = o & 7;
        f32x4 acc = {0.f,0.f,0.f,0.f};
        bf8 B0 = *(const bf8*)(ab + o*128 + (((kg ^ om7 ^ swzn))<<4));
        acc = __builtin_amdgcn_mfma_f32_16x16x32_bf16(af0, B0, acc, 0,0,0);
        bf8 B1 = *(const bf8*)(ab + o*128 + ((((4 + kg) ^ om7 ^ swzn))<<4));
        acc = __builtin_amdgcn_mfma_f32_16x16x32_bf16(af1, B1, acc, 0,0,0);
        // bias: row 64 (o_row&7 == 0), k = o
        float bias = bf2f(*(const unsigned short*)(ab + 64*128 + ((((o>>3) ^ swzn))<<4) + om7*2));
        #pragma unroll
        for (int j=0; j<4; ++j){
          int e = ebase + j;
          if (e < eend){
            int d2 = sDst[e];
            atomicAdd(&aggr[(size_t)d2*DD + o], acc[j] + bias);
          }
        }
      }
    }
  }
}

// ---------- fused NNConv-root + GRU (also emits bf16 h; zeroes aggr for next iter) ----------
#define NB 8
__global__ __launch_bounds__(256) void k_gru(float* __restrict__ h, unsigned short* __restrict__ hbf,
                      float* __restrict__ aggr,
                      const float* __restrict__ invd,
                      const float* __restrict__ cr, const float* __restrict__ cb,
                      const float* __restrict__ wihT, const float* __restrict__ whhT,
                      const float* __restrict__ bih, const float* __restrict__ bhh){
  int wid = (blockIdx.x*blockDim.x + threadIdx.x) >> 6;
  int lane = threadIdx.x & 63;
  int nb0 = wid * NB;
  if (nb0 >= NN) return;
  int cnt = NN - nb0 < NB ? NN - nb0 : NB;

  float hreg[NB], mreg[NB], mac[NB];
  #pragma unroll
  for (int t=0; t<NB; ++t){ hreg[t] = (t<cnt) ? h[(size_t)(nb0+t)*DD + lane] : 0.f; mac[t]=0.f; }
  for (int i=0; i<DD; ++i){
    float crv = cr[i*DD + lane];
    #pragma unroll
    for (int t=0; t<NB; ++t) mac[t] += __shfl(hreg[t], i) * crv;
  }
  #pragma unroll
  for (int t=0; t<NB; ++t){
    if (t < cnt){
      float id = invd[nb0+t];
      mreg[t] = lk(aggr[(size_t)(nb0+t)*DD + lane]*id + mac[t] + cb[lane]);
      aggr[(size_t)(nb0+t)*DD + lane] = 0.f;    // pre-zero for next iteration's scatter
    } else mreg[t] = 0.f;
  }
  float air[NB]={}, aiz[NB]={}, ain[NB]={}, ahr[NB]={}, ahz[NB]={}, ahn[NB]={};
  for (int i=0; i<DD; ++i){
    float w0 = wihT[i*192 + lane], w1 = wihT[i*192 + 64 + lane], w2 = wihT[i*192 + 128 + lane];
    float v0 = whhT[i*192 + lane], v1 = whhT[i*192 + 64 + lane], v2 = whhT[i*192 + 128 + lane];
    #pragma unroll
    for (int t=0; t<NB; ++t){
      float mi = __shfl(mreg[t], i), hi = __shfl(hreg[t], i);
      air[t] += mi*w0; aiz[t] += mi*w1; ain[t] += mi*w2;
      ahr[t] += hi*v0; ahz[t] += hi*v1; ahn[t] += hi*v2;
    }
  }
  float bi0 = bih[lane], bi1 = bih[64+lane], bi2 = bih[128+lane];
  float bh0 = bhh[lane], bh1 = bhh[64+lane], bh2 = bhh[128+lane];
  #pragma unroll
  for (int t=0; t<NB; ++t){
    if (t < cnt){
      float r = sg(air[t]+bi0 + ahr[t]+bh0);
      float z = sg(aiz[t]+bi1 + ahz[t]+bh1);
      float n = tanhf(ain[t]+bi2 + r*(ahn[t]+bh2));
      float nh = (1.f - z)*n + z*hreg[t];
      h[(size_t)(nb0+t)*DD + lane] = nh;
      hbf[(size_t)(nb0+t)*DD + lane] = f2bf(nh);
    }
  }
}

// ---------- heads ----------
__global__ __launch_bounds__(256) void k_jbond(const float* __restrict__ h, const int* __restrict__ idx,
                        const float* __restrict__ w1T, const float* __restrict__ b1,
                        const float* __restrict__ w2, const float* __restrict__ b2,
                        float* __restrict__ jtmp){
  int wid = (blockIdx.x*blockDim.x + threadIdx.x) >> 6;
  int lane = threadIdx.x & 63;
  if (wid >= NJ*2) return;
  int a = idx[wid];
  float f = h[(size_t)a*DD + lane];
  float acc = b1[lane];
  for (int i=0; i<DD; ++i) acc += __shfl(f, i) * w1T[i*DD + lane];
  float p = lk(acc) * w2[lane];
  #pragma unroll
  for (int off=32; off; off>>=1) p += __shfl_xor(p, off);
  if (lane == 0) jtmp[wid] = p + b2[0];
}
__global__ __launch_bounds__(256) void k_jmean(const float* __restrict__ jtmp, float* __restrict__ o){
  int j = blockIdx.x*blockDim.x + threadIdx.x;
  if (j < NJ) o[j] = 0.5f*(jtmp[2*j] + jtmp[2*j+1]);
}
__global__ __launch_bounds__(256) void k_stem1(const float* __restrict__ h, const int* __restrict__ idx,
                        const float* __restrict__ w1T, const float* __restrict__ b1,
                        float* __restrict__ st1){
  int wid = (blockIdx.x*blockDim.x + threadIdx.x) >> 6;
  int lane = threadIdx.x & 63;
  if (wid >= NS) return;
  int a = idx[wid];
  float f = h[(size_t)a*DD + lane];
  float acc = b1[lane];
  for (int i=0; i<DD; ++i) acc += __shfl(f, i) * w1T[i*DD + lane];
  st1[(size_t)wid*DD + lane] = lk(acc);
}
// w2T[k*NO + c] layout -> coalesced inner loop
__global__ __launch_bounds__(256) void k_stem2(const float* __restrict__ st1, const float* __restrict__ w2T,
                        const float* __restrict__ b2, float* __restrict__ o){
  int i = blockIdx.x*blockDim.x + threadIdx.x;
  if (i >= NS*NO) return;
  int r = i / NO, c = i - r*NO;
  float acc = b2[c];
  const float* t1 = st1 + (size_t)r*DD;
  for (int k=0; k<DD; ++k) acc += t1[k]*w2T[k*NO + c];
  o[i] = acc;
}

// ---------- Set2Set (1 step, zero init state) ----------
__global__ void k_qvec(const float* __restrict__ bih, const float* __restrict__ bhh, float* __restrict__ qv){
  int g = threadIdx.x;
  float gi = bih[g] + bhh[g];
  float gg = bih[128+g] + bhh[128+g];
  float go = bih[192+g] + bhh[192+g];
  float c = sg(gi)*tanhf(gg);
  qv[g] = sg(go)*tanhf(c);
}
__global__ __launch_bounds__(256) void k_e(const float* __restrict__ h, const float* __restrict__ qv,
                    const int* __restrict__ batch, float* __restrict__ evec, unsigned* __restrict__ emax){
  int n = (blockIdx.x*blockDim.x + threadIdx.x) >> 6;
  int lane = threadIdx.x & 63;
  if (n >= NN) return;
  float p = h[(size_t)n*DD + lane] * qv[lane];
  #pragma unroll
  for (int off=32; off; off>>=1) p += __shfl_xor(p, off);
  if (lane == 0){
    evec[n] = p;
    atomicMax(&emax[batch[n]], fenc(p));
  }
}
__global__ __launch_bounds__(256) void k_exden(float* __restrict__ evec, const unsigned* __restrict__ emax,
                        const int* __restrict__ batch, float* __restrict__ denom){
  int n = blockIdx.x*blockDim.x + threadIdx.x;
  if (n >= NN) return;
  float m = fdec(emax[batch[n]]);
  float ex = expf(evec[n] - m);
  evec[n] = ex;
  atomicAdd(&denom[batch[n]], ex);
}
__global__ __launch_bounds__(256) void k_rvec(const float* __restrict__ h, const float* __restrict__ evec,
                       const float* __restrict__ denom, const int* __restrict__ batch,
                       float* __restrict__ rvec){
  int n = (blockIdx.x*blockDim.x + threadIdx.x) >> 6;
  int lane = threadIdx.x & 63;
  if (n >= NN) return;
  int b = batch[n];
  float a = evec[n] / denom[b];
  atomicAdd(&rvec[(size_t)b*DD + lane], a * h[(size_t)n*DD + lane]);
}
__global__ __launch_bounds__(256) void k_gout(const float* __restrict__ qv, const float* __restrict__ rvec,
                       const float* __restrict__ lw, const float* __restrict__ lb, float* __restrict__ o){
  int t = blockIdx.x*blockDim.x + threadIdx.x;
  if (t >= NGG*2) return;
  int g = t >> 1, c = t & 1;
  float acc = lb[c];
  for (int j=0; j<DD; ++j) acc += qv[j]*lw[c*128 + j];
  for (int j=0; j<DD; ++j) acc += rvec[(size_t)g*DD + j]*lw[c*128 + 64 + j];
  o[g*2 + c] = acc;
}

// ---------- host ----------
extern "C" void kernel_launch(void* const* d_in, const int* in_sizes, int n_in,
                              void* d_out_, int out_size, void* d_ws, size_t ws_size,
                              hipStream_t stream){
  const float* x        = (const float*)d_in[0];
  const int*   ei       = (const int*)d_in[1];
  const float* eattr    = (const float*)d_in[2];
  const int*   jbidx    = (const int*)d_in[3];
  const int*   stidx    = (const int*)d_in[4];
  const int*   batch    = (const int*)d_in[5];
  const float* lin0_w   = (const float*)d_in[6];
  const float* lin0_b   = (const float*)d_in[7];
  const float* net1_w   = (const float*)d_in[8];
  const float* net1_b   = (const float*)d_in[9];
  const float* net2_w   = (const float*)d_in[10];
  const float* net2_b   = (const float*)d_in[11];
  const float* conv_root= (const float*)d_in[12];
  const float* conv_b   = (const float*)d_in[13];
  const float* gru_wih  = (const float*)d_in[14];
  const float* gru_whh  = (const float*)d_in[15];
  const float* gru_bih  = (const float*)d_in[16];
  const float* gru_bhh  = (const float*)d_in[17];
  const float* n2s_w1   = (const float*)d_in[18];
  const float* n2s_b1   = (const float*)d_in[19];
  const float* n2s_w2   = (const float*)d_in[20];
  const float* n2s_b2   = (const float*)d_in[21];
  const float* n2j_w1   = (const float*)d_in[22];
  const float* n2j_b1   = (const float*)d_in[23];
  const float* n2j_w2   = (const float*)d_in[24];
  const float* n2j_b2   = (const float*)d_in[25];
  const float* lstm_bih = (const float*)d_in[28];
  const float* lstm_bhh = (const float*)d_in[29];
  const float* lout_w   = (const float*)d_in[30];
  const float* lout_b   = (const float*)d_in[31];
  float* out = (float*)d_out_;

  const int* src = ei;
  const int* dst = ei + NE;

  char* ws = (char*)d_ws;
  size_t off = 0;
  auto alloc = [&](size_t bytes)->void*{
    void* p = ws + off; off = (off + bytes + 255) & ~(size_t)255; return p;
  };
  float* h    = (float*)alloc((size_t)NN*DD*4);
  float* aggr = (float*)alloc((size_t)NN*DD*4);
  unsigned short* hbf = (unsigned short*)alloc((size_t)NPAD*DD*2);
  unsigned short* e1s = (unsigned short*)alloc((size_t)NE*DD*2);
  unsigned short* w2x = (unsigned short*)alloc((size_t)CTOT*DD*2);
  int* degS   = (int*)alloc((size_t)NPAD*4);          // zeroed (contiguous group start)
  int* cnt    = (int*)alloc((size_t)NPAD*4);          // zeroed
  float* invd = (float*)alloc((size_t)NN*4);          // zeroed (group end)
  int* rowptr = (int*)alloc((size_t)(NPAD+1)*4);
  int* sSrc   = (int*)alloc((size_t)NE*4);
  int* sDst   = (int*)alloc((size_t)NE*4);
  int* sEid   = (int*)alloc((size_t)NE*4);
  float* wihT = (float*)alloc((size_t)DD*192*4);
  float* whhT = (float*)alloc((size_t)DD*192*4);
  float* w1jT = (float*)alloc((size_t)DD*DD*4);
  float* w1sT = (float*)alloc((size_t)DD*DD*4);
  float* w2sT = (float*)alloc((size_t)DD*NO*4);
  float* evec = (float*)alloc((size_t)NN*4);
  unsigned* emax = (unsigned*)alloc((size_t)NGG*4);   // zeroed (contiguous group)
  float* denom = (float*)alloc((size_t)NGG*4);        // zeroed
  float* rvec  = (float*)alloc((size_t)NGG*DD*4);     // zeroed (group end)
  float* qv    = (float*)alloc((size_t)DD*4);
  float* jtmp  = (float*)alloc((size_t)NJ*2*4);
  float* st1   = (float*)alloc((size_t)NS*DD*4);

  const int LDSB = 16*ASTRIDE;   // 133632
  hipFuncSetAttribute((const void*)k_fused8, hipFuncAttributeMaxDynamicSharedMemorySize, LDSB);

  // ---- setup ----
  hipMemsetAsync(degS, 0, (size_t)((char*)invd + NN*4 - (char*)degS), stream);  // degS+cnt+invd
  hipMemsetAsync(aggr, 0, (size_t)NN*DD*4, stream);                             // iter-1 scatter target
  k_lin0<<<(NPAD+3)/4, 256, 0, stream>>>(x, lin0_w, lin0_b, h, hbf);
  k_w2x<<<1040, 256, 0, stream>>>(net2_w, net2_b, w2x);
  k_tr<<<48, 256, 0, stream>>>(gru_wih, wihT, 192, 64);
  k_tr<<<48, 256, 0, stream>>>(gru_whh, whhT, 192, 64);
  k_tr<<<16, 256, 0, stream>>>(n2j_w1, w1jT, 64, 64);
  k_tr<<<16, 256, 0, stream>>>(n2s_w1, w1sT, 64, 64);
  k_tr<<<27, 256, 0, stream>>>(n2s_w2, w2sT, NO, DD);
  k_deg<<<391, 256, 0, stream>>>(dst, invd);
  k_invd<<<98, 256, 0, stream>>>(invd);
  // edge sort by src
  k_hist<<<391, 256, 0, stream>>>(src, degS);
  k_scan<<<1, 1024, 0, stream>>>(degS, rowptr);
  k_scatter<<<391, 256, 0, stream>>>(src, dst, rowptr, cnt, sSrc, sDst, sEid);
  k_e1s<<<25000, 256, 0, stream>>>(eattr, net1_w, net1_b, sEid, e1s);

  // ---- 6 message-passing + GRU iterations ----
  for (int it=0; it<6; ++it){
    k_fused8<<<NBLK, 1024, LDSB, stream>>>(w2x, hbf, e1s, sDst, rowptr, aggr);
    k_gru<<<782, 256, 0, stream>>>(h, hbf, aggr, invd, conv_root, conv_b, wihT, whhT, gru_bih, gru_bhh);
  }

  // ---- heads ----
  k_jbond<<<512, 256, 0, stream>>>(h, jbidx, w1jT, n2j_b1, n2j_w2, n2j_b2, jtmp);
  k_jmean<<<4, 256, 0, stream>>>(jtmp, out + NGG*2 + NS*NO);
  k_stem1<<<512, 256, 0, stream>>>(h, stidx, w1sT, n2s_b1, st1);
  k_stem2<<<840, 256, 0, stream>>>(st1, w2sT, n2s_b2, out + NGG*2);

  // ---- Set2Set ----
  hipMemsetAsync(emax, 0, (size_t)((char*)(rvec + NGG*DD) - (char*)emax), stream); // emax+denom+rvec
  k_qvec<<<1, 64, 0, stream>>>(lstm_bih, lstm_bhh, qv);
  k_e<<<6250, 256, 0, stream>>>(h, qv, batch, evec, emax);
  k_exden<<<98, 256, 0, stream>>>(evec, emax, batch, denom);
  k_rvec<<<6250, 256, 0, stream>>>(h, evec, denom, batch, rvec);
  k_gout<<<4, 256, 0, stream>>>(qv, rvec, lout_w, lout_b, out);
}

// Round 6
// 1409.463 us; speedup vs baseline: 1.1385x; 1.1385x over previous
//
#include <hip/hip_runtime.h>
#include <stdint.h>
#include <stddef.h>

#define NN 25000     // nodes
#define NPAD 25008   // 1563*16
#define NBLK 1563    // node blocks of 16
#define NE 100000    // edges
#define FEAT 16
#define DD 64
#define NGG 512
#define NJ 1024
#define NS 2048
#define NO 105
#define SLOPE 0.01f
#define CTOT 4160    // 4096 A-columns + 64 bias columns
#define ASTRIDE 8352 // bytes per node row in LDS: 65 o-rows * 128B = 8320, pad to 8352 (16B aligned)

typedef short bf8 __attribute__((ext_vector_type(8)));   // 8 bf16 raw bits (4 VGPR)
typedef float f32x4 __attribute__((ext_vector_type(4)));

__device__ __forceinline__ float lk(float v){ return v > 0.f ? v : SLOPE*v; }
__device__ __forceinline__ unsigned short f2bf(float f){
  unsigned int x = __float_as_uint(f);
  x += 0x7fffu + ((x>>16)&1u);           // round-to-nearest-even
  return (unsigned short)(x>>16);
}
__device__ __forceinline__ float bf2f(unsigned short u){ return __uint_as_float(((unsigned int)u)<<16); }
__device__ __forceinline__ float sg(float x){ return 1.f/(1.f+expf(-x)); }
__device__ __forceinline__ unsigned fenc(float f){ unsigned u = __float_as_uint(f); return (u & 0x80000000u) ? ~u : (u | 0x80000000u); }
__device__ __forceinline__ float fdec(unsigned k){ unsigned u = (k & 0x80000000u) ? (k ^ 0x80000000u) : ~k; return __uint_as_float(u); }

// ---------- setup kernels ----------

// out = leaky(x @ lin0_w.T + lin0_b); also writes bf16 copy; zero-fills hbf pad rows
__global__ __launch_bounds__(256) void k_lin0(const float* __restrict__ x, const float* __restrict__ w,
                       const float* __restrict__ b, float* __restrict__ h, unsigned short* __restrict__ hbf){
  int wid = (blockIdx.x*blockDim.x + threadIdx.x) >> 6;
  int lane = threadIdx.x & 63;
  if (wid >= NPAD) return;
  if (wid >= NN){ hbf[(size_t)wid*DD + lane] = 0; return; }
  float xv = lane < FEAT ? x[wid*FEAT + lane] : 0.f;
  float acc = b[lane];
  #pragma unroll
  for (int f=0; f<FEAT; ++f) acc += __shfl(xv, f) * w[lane*FEAT + f];
  float v = lk(acc);
  h[wid*DD + lane] = v;
  hbf[(size_t)wid*DD + lane] = f2bf(v);
}

// w2x[c*64+i]: c<4096 -> bf16(net2_w flat[i*4096+c]) ; c=4096+o -> bf16(net2_b[i*64+o])
__global__ __launch_bounds__(256) void k_w2x(const float* __restrict__ w2, const float* __restrict__ b2,
                                             unsigned short* __restrict__ o){
  int t = blockIdx.x*blockDim.x + threadIdx.x;
  if (t >= CTOT*DD) return;
  int c = t >> 6, i = t & 63;
  float v = (c < 4096) ? w2[(size_t)i*4096 + c] : b2[i*64 + (c - 4096)];
  o[t] = f2bf(v);
}

// generic transpose: T[c*R + r] = M[r*C + c]
__global__ __launch_bounds__(256) void k_tr(const float* __restrict__ m, float* __restrict__ t, int R, int C){
  int i = blockIdx.x*blockDim.x + threadIdx.x;
  if (i >= R*C) return;
  int r = i / C, c = i - r*C;
  t[c*R + r] = m[i];
}

// histograms: degS[src]++, degD[dst]++
__global__ __launch_bounds__(256) void k_hist(const int* __restrict__ src, const int* __restrict__ dst,
                                              int* __restrict__ degS, int* __restrict__ degD){
  int e = blockIdx.x*blockDim.x + threadIdx.x;
  if (e < NE){ atomicAdd(&degS[src[e]], 1); atomicAdd(&degD[dst[e]], 1); }
}
__global__ __launch_bounds__(256) void k_invd(const int* __restrict__ degD, float* __restrict__ d){
  int n = blockIdx.x*blockDim.x + threadIdx.x;
  if (n < NN) d[n] = degD[n] > 0 ? 1.f/(float)degD[n] : 0.f;
}

// single-block scan via wave shuffles: rowptr[0..NPAD] from deg[0..NPAD)
__global__ __launch_bounds__(1024) void k_scan(const int* __restrict__ deg, int* __restrict__ rowptr){
  __shared__ int wsum[16];
  __shared__ int base;
  int tid = threadIdx.x, lane = tid & 63, wv = tid >> 6;
  if (tid == 0){ base = 0; rowptr[0] = 0; }
  __syncthreads();
  for (int c0 = 0; c0 < NPAD; c0 += 1024){
    int i = c0 + tid;
    int v = (i < NPAD) ? deg[i] : 0;
    int s = v;
    #pragma unroll
    for (int off=1; off<64; off<<=1){
      int t = __shfl_up(s, off);
      if (lane >= off) s += t;
    }
    if (lane == 63) wsum[wv] = s;
    __syncthreads();
    if (wv == 0 && lane < 16){
      int ws = wsum[lane];
      #pragma unroll
      for (int off=1; off<16; off<<=1){
        int t = __shfl_up(ws, off);
        if (lane >= off) ws += t;
      }
      wsum[lane] = ws;
    }
    __syncthreads();
    int wbase = (wv == 0) ? 0 : wsum[wv-1];
    if (i < NPAD) rowptr[i+1] = base + wbase + s;
    __syncthreads();
    if (tid == 0) base += wsum[15];
    __syncthreads();
  }
}

// scatter: src-sorted position p gets original edge id; also dst-sorted position for p
__global__ __launch_bounds__(256) void k_scatter(const int* __restrict__ src, const int* __restrict__ dst,
                         const int* __restrict__ rowptr, int* __restrict__ cnt,
                         const int* __restrict__ rowptrD, int* __restrict__ cntD,
                         int* __restrict__ sEid, int* __restrict__ sDpos){
  int e = blockIdx.x*blockDim.x + threadIdx.x;
  if (e >= NE) return;
  int s = src[e], d = dst[e];
  int pos = rowptr[s] + atomicAdd(&cnt[s], 1);
  sEid[pos] = e;
  sDpos[pos] = rowptrD[d] + atomicAdd(&cntD[d], 1);
}

// e1 sorted: e1s[pos][k] = bf16(leaky(edge_attr[sEid[pos]] @ net1_w.T + net1_b))
__global__ __launch_bounds__(256) void k_e1s(const float* __restrict__ ea, const float* __restrict__ w,
                     const float* __restrict__ b, const int* __restrict__ sEid,
                     unsigned short* __restrict__ e1s){
  int t = blockIdx.x*blockDim.x + threadIdx.x;   // t = pos*64 + k
  if (t >= NE*DD) return;
  int pos = t >> 6, k = t & 63;
  int e = sEid[pos];
  float acc = b[k];
  #pragma unroll
  for (int a=0; a<4; ++a) acc += ea[e*4+a] * w[k*4+a];
  e1s[t] = f2bf(lk(acc));
}

// graph histogram for batch-CSR
__global__ __launch_bounds__(256) void k_ghist(const int* __restrict__ batch, int* __restrict__ ghist){
  int n = blockIdx.x*blockDim.x + threadIdx.x;
  if (n < NN) atomicAdd(&ghist[batch[n]], 1);
}
// scan over 512 graph counts (single block of 512)
__global__ __launch_bounds__(512) void k_gscan(const int* __restrict__ ghist, int* __restrict__ gptr){
  __shared__ int wsum[8];
  int tid = threadIdx.x, lane = tid & 63, wv = tid >> 6;
  int s = ghist[tid];
  #pragma unroll
  for (int off=1; off<64; off<<=1){
    int t = __shfl_up(s, off);
    if (lane >= off) s += t;
  }
  if (lane == 63) wsum[wv] = s;
  __syncthreads();
  if (wv == 0 && lane < 8){
    int ws = wsum[lane];
    #pragma unroll
    for (int off=1; off<8; off<<=1){
      int t = __shfl_up(ws, off);
      if (lane >= off) ws += t;
    }
    wsum[lane] = ws;
  }
  __syncthreads();
  if (tid == 0) gptr[0] = 0;
  int wbase = (wv == 0) ? 0 : wsum[wv-1];
  gptr[tid+1] = wbase + s;
}

// ---------- fused: per 16-node block, A-tile in LDS (swizzled), then MFMA edge-GEMMs ----------
// Phase A: A[n][c] = sum_i w2x[c][i]*hbf[n][i] (c = o*64+k; c=4096+o is bias), bf16 into LDS.
//   LDS addr for (n, c): o=c>>6, k=c&63, slot_lin=k>>3;
//   byte = n*ASTRIDE + o*128 + ((slot_lin ^ (o&7) ^ ((n&1)<<2))<<4) + (k&7)*2   [XOR swizzle, both sides]
// Phase B: wave wv owns node n0+wv; per 16-edge M-tile: MFMA( e1 rows, A64[o][k] cols ),
//   plain store of msg row into dst-sorted msgbuf (NO atomics).
__global__ __launch_bounds__(1024) void k_fused8(const unsigned short* __restrict__ w2x,
                                                const unsigned short* __restrict__ hbf,
                                                const unsigned short* __restrict__ e1s,
                                                const int* __restrict__ sDpos,
                                                const int* __restrict__ rowptr,
                                                float* __restrict__ msgbuf){
  extern __shared__ char smem[];
  int lane = threadIdx.x & 63;
  int wv   = threadIdx.x >> 6;           // 0..15
  int n0   = blockIdx.x * 16;
  int r16 = lane & 15, kg = lane >> 4;

  // persistent B-fragments: bf16 h rows of the 16 nodes (col = node r16)
  const unsigned short* hp = hbf + (size_t)(n0 + r16)*DD;
  bf8 bh0 = *(const bf8*)(hp + kg*8);
  bf8 bh1 = *(const bf8*)(hp + 32 + kg*8);

  // phase A: 260 c-tiles round-robin over 16 waves; lane holds (n=r16, c=t*16+kg*4+j)
  {
    int slot_w0 = kg >> 1;               // (t&3)*2 added per-t
    int swzn = (r16 & 1) << 2;
    for (int t = wv; t < 260; t += 16){
      const unsigned short* wp = w2x + (size_t)t*1024 + r16*64;
      bf8 a0 = *(const bf8*)(wp + kg*8);
      bf8 a1 = *(const bf8*)(wp + 32 + kg*8);
      f32x4 acc = {0.f,0.f,0.f,0.f};
      acc = __builtin_amdgcn_mfma_f32_16x16x32_bf16(a0, bh0, acc, 0,0,0);
      acc = __builtin_amdgcn_mfma_f32_16x16x32_bf16(a1, bh1, acc, 0,0,0);
      unsigned u0 = (unsigned)f2bf(acc[0]) | ((unsigned)f2bf(acc[1]) << 16);
      unsigned u1 = (unsigned)f2bf(acc[2]) | ((unsigned)f2bf(acc[3]) << 16);
      unsigned long long ull = (unsigned long long)u0 | ((unsigned long long)u1 << 32);
      int o = t >> 2;
      int slot = (((t & 3) * 2 + slot_w0) ^ (o & 7) ^ swzn);
      *(unsigned long long*)(smem + (size_t)r16*ASTRIDE + o*128 + (slot<<4) + ((kg & 1) * 8)) = ull;
    }
  }
  __syncthreads();

  // phase B: wave wv = node n0+wv
  {
    int node = n0 + wv;
    int estart = rowptr[node], eend = rowptr[node + 1];
    const char* ab = smem + (size_t)wv*ASTRIDE;
    int swzn = (wv & 1) << 2;
    for (int eg = estart; eg < eend; eg += 16){
      // A-frags: edge rows (row = r16 -> edge eg+r16), zero-filled beyond degree
      bf8 af0 = {0,0,0,0,0,0,0,0}, af1 = {0,0,0,0,0,0,0,0};
      int er = eg + r16;
      if (er < eend){
        af0 = *(const bf8*)(e1s + (size_t)er*DD + kg*8);
        af1 = *(const bf8*)(e1s + (size_t)er*DD + 32 + kg*8);
      }
      // dst-sorted positions for this lane's 4 output edges (row = kg*4+j)
      int ebase = eg + kg*4;
      int dp[4];
      #pragma unroll
      for (int j=0; j<4; ++j){
        int e = ebase + j;
        dp[j] = (e < eend) ? sDpos[e] : -1;
      }
      #pragma unroll
      for (int nt=0; nt<4; ++nt){
        int o = nt*16 + r16;
        int om7 = o & 7;
        f32x4 acc = {0.f,0.f,0.f,0.f};
        bf8 B0 = *(const bf8*)(ab + o*128 + (((kg ^ om7 ^ swzn))<<4));
        acc = __builtin_amdgcn_mfma_f32_16x16x32_bf16(af0, B0, acc, 0,0,0);
        bf8 B1 = *(const bf8*)(ab + o*128 + ((((4 + kg) ^ om7 ^ swzn))<<4));
        acc = __builtin_amdgcn_mfma_f32_16x16x32_bf16(af1, B1, acc, 0,0,0);
        // bias: row 64 (o_row&7 == 0), k = o
        float bias = bf2f(*(const unsigned short*)(ab + 64*128 + ((((o>>3) ^ swzn))<<4) + om7*2));
        #pragma unroll
        for (int j=0; j<4; ++j){
          if (dp[j] >= 0)
            msgbuf[(size_t)dp[j]*DD + o] = acc[j] + bias;
        }
      }
    }
  }
}

// ---------- fused dst-segment-sum + NNConv-root + GRU (also emits bf16 h) ----------
#define NB 8
__global__ __launch_bounds__(256) void k_gru(float* __restrict__ h, unsigned short* __restrict__ hbf,
                      const float* __restrict__ msgbuf, const int* __restrict__ rowptrD,
                      const float* __restrict__ invd,
                      const float* __restrict__ cr, const float* __restrict__ cb,
                      const float* __restrict__ wihT, const float* __restrict__ whhT,
                      const float* __restrict__ bih, const float* __restrict__ bhh){
  int wid = (blockIdx.x*blockDim.x + threadIdx.x) >> 6;
  int lane = threadIdx.x & 63;
  int nb0 = wid * NB;
  if (nb0 >= NN) return;
  int cnt = NN - nb0 < NB ? NN - nb0 : NB;

  float hreg[NB], mreg[NB], mac[NB];
  #pragma unroll
  for (int t=0; t<NB; ++t){ hreg[t] = (t<cnt) ? h[(size_t)(nb0+t)*DD + lane] : 0.f; mac[t]=0.f; }
  for (int i=0; i<DD; ++i){
    float crv = cr[i*DD + lane];
    #pragma unroll
    for (int t=0; t<NB; ++t) mac[t] += __shfl(hreg[t], i) * crv;
  }
  #pragma unroll
  for (int t=0; t<NB; ++t){
    if (t < cnt){
      float ms = 0.f;
      int pa = rowptrD[nb0+t], pb = rowptrD[nb0+t+1];
      for (int p=pa; p<pb; ++p) ms += msgbuf[(size_t)p*DD + lane];
      float id = invd[nb0+t];
      mreg[t] = lk(ms*id + mac[t] + cb[lane]);
    } else mreg[t] = 0.f;
  }
  float air[NB]={}, aiz[NB]={}, ain[NB]={}, ahr[NB]={}, ahz[NB]={}, ahn[NB]={};
  for (int i=0; i<DD; ++i){
    float w0 = wihT[i*192 + lane], w1 = wihT[i*192 + 64 + lane], w2 = wihT[i*192 + 128 + lane];
    float v0 = whhT[i*192 + lane], v1 = whhT[i*192 + 64 + lane], v2 = whhT[i*192 + 128 + lane];
    #pragma unroll
    for (int t=0; t<NB; ++t){
      float mi = __shfl(mreg[t], i), hi = __shfl(hreg[t], i);
      air[t] += mi*w0; aiz[t] += mi*w1; ain[t] += mi*w2;
      ahr[t] += hi*v0; ahz[t] += hi*v1; ahn[t] += hi*v2;
    }
  }
  float bi0 = bih[lane], bi1 = bih[64+lane], bi2 = bih[128+lane];
  float bh0 = bhh[lane], bh1 = bhh[64+lane], bh2 = bhh[128+lane];
  #pragma unroll
  for (int t=0; t<NB; ++t){
    if (t < cnt){
      float r = sg(air[t]+bi0 + ahr[t]+bh0);
      float z = sg(aiz[t]+bi1 + ahz[t]+bh1);
      float n = tanhf(ain[t]+bi2 + r*(ahn[t]+bh2));
      float nh = (1.f - z)*n + z*hreg[t];
      h[(size_t)(nb0+t)*DD + lane] = nh;
      hbf[(size_t)(nb0+t)*DD + lane] = f2bf(nh);
    }
  }
}

// ---------- heads ----------
__global__ __launch_bounds__(256) void k_jbond(const float* __restrict__ h, const int* __restrict__ idx,
                        const float* __restrict__ w1T, const float* __restrict__ b1,
                        const float* __restrict__ w2, const float* __restrict__ b2,
                        float* __restrict__ jtmp){
  int wid = (blockIdx.x*blockDim.x + threadIdx.x) >> 6;
  int lane = threadIdx.x & 63;
  if (wid >= NJ*2) return;
  int a = idx[wid];
  float f = h[(size_t)a*DD + lane];
  float acc = b1[lane];
  for (int i=0; i<DD; ++i) acc += __shfl(f, i) * w1T[i*DD + lane];
  float p = lk(acc) * w2[lane];
  #pragma unroll
  for (int off=32; off; off>>=1) p += __shfl_xor(p, off);
  if (lane == 0) jtmp[wid] = p + b2[0];
}
__global__ __launch_bounds__(256) void k_jmean(const float* __restrict__ jtmp, float* __restrict__ o){
  int j = blockIdx.x*blockDim.x + threadIdx.x;
  if (j < NJ) o[j] = 0.5f*(jtmp[2*j] + jtmp[2*j+1]);
}
__global__ __launch_bounds__(256) void k_stem1(const float* __restrict__ h, const int* __restrict__ idx,
                        const float* __restrict__ w1T, const float* __restrict__ b1,
                        float* __restrict__ st1){
  int wid = (blockIdx.x*blockDim.x + threadIdx.x) >> 6;
  int lane = threadIdx.x & 63;
  if (wid >= NS) return;
  int a = idx[wid];
  float f = h[(size_t)a*DD + lane];
  float acc = b1[lane];
  for (int i=0; i<DD; ++i) acc += __shfl(f, i) * w1T[i*DD + lane];
  st1[(size_t)wid*DD + lane] = lk(acc);
}
// w2T[k*NO + c] layout -> coalesced inner loop
__global__ __launch_bounds__(256) void k_stem2(const float* __restrict__ st1, const float* __restrict__ w2T,
                        const float* __restrict__ b2, float* __restrict__ o){
  int i = blockIdx.x*blockDim.x + threadIdx.x;
  if (i >= NS*NO) return;
  int r = i / NO, c = i - r*NO;
  float acc = b2[c];
  const float* t1 = st1 + (size_t)r*DD;
  for (int k=0; k<DD; ++k) acc += t1[k]*w2T[k*NO + c];
  o[i] = acc;
}

// ---------- Set2Set (1 step, zero init state) ----------
__global__ void k_qvec(const float* __restrict__ bih, const float* __restrict__ bhh, float* __restrict__ qv){
  int g = threadIdx.x;
  float gi = bih[g] + bhh[g];
  float gg = bih[128+g] + bhh[128+g];
  float go = bih[192+g] + bhh[192+g];
  float c = sg(gi)*tanhf(gg);
  qv[g] = sg(go)*tanhf(c);
}
__global__ __launch_bounds__(256) void k_e(const float* __restrict__ h, const float* __restrict__ qv,
                    const int* __restrict__ batch, float* __restrict__ evec, unsigned* __restrict__ emax){
  int n = (blockIdx.x*blockDim.x + threadIdx.x) >> 6;
  int lane = threadIdx.x & 63;
  if (n >= NN) return;
  float p = h[(size_t)n*DD + lane] * qv[lane];
  #pragma unroll
  for (int off=32; off; off>>=1) p += __shfl_xor(p, off);
  if (lane == 0){
    evec[n] = p;
    atomicMax(&emax[batch[n]], fenc(p));
  }
}
// wave per graph: rvec[g] = sum(ex_n * h_n) / sum(ex_n), single pass over batch-CSR
__global__ __launch_bounds__(256) void k_gsum(const float* __restrict__ h, const float* __restrict__ evec,
                       const unsigned* __restrict__ emax, const int* __restrict__ gptr,
                       float* __restrict__ rvec){
  int g = (blockIdx.x*blockDim.x + threadIdx.x) >> 6;
  int lane = threadIdx.x & 63;
  if (g >= NGG) return;
  int a = gptr[g], b = gptr[g+1];
  if (a >= b){ rvec[(size_t)g*DD + lane] = 0.f; return; }
  float m = fdec(emax[g]);
  float s = 0.f, vacc = 0.f;
  for (int n=a; n<b; ++n){
    float ex = expf(evec[n] - m);
    s += ex;
    vacc += ex * h[(size_t)n*DD + lane];
  }
  rvec[(size_t)g*DD + lane] = vacc / s;
}
__global__ __launch_bounds__(256) void k_gout(const float* __restrict__ qv, const float* __restrict__ rvec,
                       const float* __restrict__ lw, const float* __restrict__ lb, float* __restrict__ o){
  int t = blockIdx.x*blockDim.x + threadIdx.x;
  if (t >= NGG*2) return;
  int g = t >> 1, c = t & 1;
  float acc = lb[c];
  for (int j=0; j<DD; ++j) acc += qv[j]*lw[c*128 + j];
  for (int j=0; j<DD; ++j) acc += rvec[(size_t)g*DD + j]*lw[c*128 + 64 + j];
  o[g*2 + c] = acc;
}

// ---------- host ----------
extern "C" void kernel_launch(void* const* d_in, const int* in_sizes, int n_in,
                              void* d_out_, int out_size, void* d_ws, size_t ws_size,
                              hipStream_t stream){
  const float* x        = (const float*)d_in[0];
  const int*   ei       = (const int*)d_in[1];
  const float* eattr    = (const float*)d_in[2];
  const int*   jbidx    = (const int*)d_in[3];
  const int*   stidx    = (const int*)d_in[4];
  const int*   batch    = (const int*)d_in[5];
  const float* lin0_w   = (const float*)d_in[6];
  const float* lin0_b   = (const float*)d_in[7];
  const float* net1_w   = (const float*)d_in[8];
  const float* net1_b   = (const float*)d_in[9];
  const float* net2_w   = (const float*)d_in[10];
  const float* net2_b   = (const float*)d_in[11];
  const float* conv_root= (const float*)d_in[12];
  const float* conv_b   = (const float*)d_in[13];
  const float* gru_wih  = (const float*)d_in[14];
  const float* gru_whh  = (const float*)d_in[15];
  const float* gru_bih  = (const float*)d_in[16];
  const float* gru_bhh  = (const float*)d_in[17];
  const float* n2s_w1   = (const float*)d_in[18];
  const float* n2s_b1   = (const float*)d_in[19];
  const float* n2s_w2   = (const float*)d_in[20];
  const float* n2s_b2   = (const float*)d_in[21];
  const float* n2j_w1   = (const float*)d_in[22];
  const float* n2j_b1   = (const float*)d_in[23];
  const float* n2j_w2   = (const float*)d_in[24];
  const float* n2j_b2   = (const float*)d_in[25];
  const float* lstm_bih = (const float*)d_in[28];
  const float* lstm_bhh = (const float*)d_in[29];
  const float* lout_w   = (const float*)d_in[30];
  const float* lout_b   = (const float*)d_in[31];
  float* out = (float*)d_out_;

  const int* src = ei;
  const int* dst = ei + NE;

  char* ws = (char*)d_ws;
  size_t off = 0;
  auto alloc = [&](size_t bytes)->void*{
    void* p = ws + off; off = (off + bytes + 255) & ~(size_t)255; return p;
  };
  float* h    = (float*)alloc((size_t)NN*DD*4);
  float* msgbuf = (float*)alloc((size_t)NE*DD*4);
  unsigned short* hbf = (unsigned short*)alloc((size_t)NPAD*DD*2);
  unsigned short* e1s = (unsigned short*)alloc((size_t)NE*DD*2);
  unsigned short* w2x = (unsigned short*)alloc((size_t)CTOT*DD*2);
  // ---- zeroed group (one memset) ----
  int* degS   = (int*)alloc((size_t)NPAD*4);
  int* cnt    = (int*)alloc((size_t)NPAD*4);
  int* degD   = (int*)alloc((size_t)NPAD*4);
  int* cntD   = (int*)alloc((size_t)NPAD*4);
  int* ghist  = (int*)alloc((size_t)NGG*4);
  unsigned* emax = (unsigned*)alloc((size_t)NGG*4);   // end of zeroed group
  char* zend = ws + off;
  // ---- rest ----
  int* rowptr  = (int*)alloc((size_t)(NPAD+1)*4);
  int* rowptrD = (int*)alloc((size_t)(NPAD+1)*4);
  int* gptr    = (int*)alloc((size_t)(NGG+1)*4);
  int* sEid   = (int*)alloc((size_t)NE*4);
  int* sDpos  = (int*)alloc((size_t)NE*4);
  float* invd = (float*)alloc((size_t)NN*4);
  float* wihT = (float*)alloc((size_t)DD*192*4);
  float* whhT = (float*)alloc((size_t)DD*192*4);
  float* w1jT = (float*)alloc((size_t)DD*DD*4);
  float* w1sT = (float*)alloc((size_t)DD*DD*4);
  float* w2sT = (float*)alloc((size_t)DD*NO*4);
  float* evec = (float*)alloc((size_t)NN*4);
  float* rvec  = (float*)alloc((size_t)NGG*DD*4);
  float* qv    = (float*)alloc((size_t)DD*4);
  float* jtmp  = (float*)alloc((size_t)NJ*2*4);
  float* st1   = (float*)alloc((size_t)NS*DD*4);

  const int LDSB = 16*ASTRIDE;   // 133632
  hipFuncSetAttribute((const void*)k_fused8, hipFuncAttributeMaxDynamicSharedMemorySize, LDSB);

  // ---- setup ----
  hipMemsetAsync(degS, 0, (size_t)(zend - (char*)degS), stream);  // degS,cnt,degD,cntD,ghist,emax
  k_lin0<<<(NPAD+3)/4, 256, 0, stream>>>(x, lin0_w, lin0_b, h, hbf);
  k_w2x<<<1040, 256, 0, stream>>>(net2_w, net2_b, w2x);
  k_tr<<<48, 256, 0, stream>>>(gru_wih, wihT, 192, 64);
  k_tr<<<48, 256, 0, stream>>>(gru_whh, whhT, 192, 64);
  k_tr<<<16, 256, 0, stream>>>(n2j_w1, w1jT, 64, 64);
  k_tr<<<16, 256, 0, stream>>>(n2s_w1, w1sT, 64, 64);
  k_tr<<<27, 256, 0, stream>>>(n2s_w2, w2sT, NO, DD);
  // edge sorts (src-CSR and dst-CSR) + batch-CSR
  k_hist<<<391, 256, 0, stream>>>(src, dst, degS, degD);
  k_invd<<<98, 256, 0, stream>>>(degD, invd);
  k_scan<<<1, 1024, 0, stream>>>(degS, rowptr);
  k_scan<<<1, 1024, 0, stream>>>(degD, rowptrD);
  k_scatter<<<391, 256, 0, stream>>>(src, dst, rowptr, cnt, rowptrD, cntD, sEid, sDpos);
  k_e1s<<<25000, 256, 0, stream>>>(eattr, net1_w, net1_b, sEid, e1s);
  k_ghist<<<98, 256, 0, stream>>>(batch, ghist);
  k_gscan<<<1, 512, 0, stream>>>(ghist, gptr);

  // ---- 6 message-passing + GRU iterations (atomic-free) ----
  for (int it=0; it<6; ++it){
    k_fused8<<<NBLK, 1024, LDSB, stream>>>(w2x, hbf, e1s, sDpos, rowptr, msgbuf);
    k_gru<<<782, 256, 0, stream>>>(h, hbf, msgbuf, rowptrD, invd, conv_root, conv_b, wihT, whhT, gru_bih, gru_bhh);
  }

  // ---- heads ----
  k_jbond<<<512, 256, 0, stream>>>(h, jbidx, w1jT, n2j_b1, n2j_w2, n2j_b2, jtmp);
  k_jmean<<<4, 256, 0, stream>>>(jtmp, out + NGG*2 + NS*NO);
  k_stem1<<<512, 256, 0, stream>>>(h, stidx, w1sT, n2s_b1, st1);
  k_stem2<<<840, 256, 0, stream>>>(st1, w2sT, n2s_b2, out + NGG*2);

  // ---- Set2Set ----
  k_qvec<<<1, 64, 0, stream>>>(lstm_bih, lstm_bhh, qv);
  k_e<<<6250, 256, 0, stream>>>(h, qv, batch, evec, emax);
  k_gsum<<<128, 256, 0, stream>>>(h, evec, emax, gptr, rvec);
  k_gout<<<4, 256, 0, stream>>>(qv, rvec, lout_w, lout_b, out);
}

// Round 7
// 1044.706 us; speedup vs baseline: 1.5360x; 1.3491x over previous
//
#include <hip/hip_runtime.h>
#include <stdint.h>
#include <stddef.h>

#define NN 25000     // nodes
#define NPAD 25008   // 1563*16
#define NBLK 1563    // node blocks of 16
#define NE 100000    // edges
#define FEAT 16
#define DD 64
#define NGG 512
#define NJ 1024
#define NS 2048
#define NO 105
#define SLOPE 0.01f
#define NQ 4         // o-quarters
#define TPQ 65       // tiles per quarter: 64 W-tiles + 1 bias tile
#define W2T_ELEMS (NQ*TPQ*1024)   // 266240 bf16
#define NSTRIDE 2112 // bytes per node in LDS: 16 o-rows*128 + 32 bias + 32 pad
#define LDSB (16*NSTRIDE)         // 33792

typedef short bf8 __attribute__((ext_vector_type(8)));   // 8 bf16 raw bits (4 VGPR)
typedef float f32x4 __attribute__((ext_vector_type(4)));

__device__ __forceinline__ float lk(float v){ return v > 0.f ? v : SLOPE*v; }
__device__ __forceinline__ unsigned short f2bf(float f){
  unsigned int x = __float_as_uint(f);
  x += 0x7fffu + ((x>>16)&1u);           // round-to-nearest-even
  return (unsigned short)(x>>16);
}
__device__ __forceinline__ float bf2f(unsigned short u){ return __uint_as_float(((unsigned int)u)<<16); }
__device__ __forceinline__ float sg(float x){ return 1.f/(1.f+expf(-x)); }
__device__ __forceinline__ unsigned fenc(float f){ unsigned u = __float_as_uint(f); return (u & 0x80000000u) ? ~u : (u | 0x80000000u); }
__device__ __forceinline__ float fdec(unsigned k){ unsigned u = (k & 0x80000000u) ? (k ^ 0x80000000u) : ~k; return __uint_as_float(u); }

// ---------- setup kernels ----------

// out = leaky(x @ lin0_w.T + lin0_b); also writes bf16 copy; zero-fills hbf pad rows
__global__ __launch_bounds__(256) void k_lin0(const float* __restrict__ x, const float* __restrict__ w,
                       const float* __restrict__ b, float* __restrict__ h, unsigned short* __restrict__ hbf){
  int wid = (blockIdx.x*blockDim.x + threadIdx.x) >> 6;
  int lane = threadIdx.x & 63;
  if (wid >= NPAD) return;
  if (wid >= NN){ hbf[(size_t)wid*DD + lane] = 0; return; }
  float xv = lane < FEAT ? x[wid*FEAT + lane] : 0.f;
  float acc = b[lane];
  #pragma unroll
  for (int f=0; f<FEAT; ++f) acc += __shfl(xv, f) * w[lane*FEAT + f];
  float v = lk(acc);
  h[wid*DD + lane] = v;
  hbf[(size_t)wid*DD + lane] = f2bf(v);
}

// tile-major reordered W2 (+h-contracted-bias columns), bf16.
// u = ((oq*65+tq)*2 + kc)*512 + lane*8 + j ; r16=lane&15, kg=lane>>4 ; i = kc*32+kg*8+j
// tq<64: c = oq*1024 + tq*16 + r16 -> val = net2_w.T flat [i*4096 + c]  (== W2[i*64+o][k], c=o*64+k)
// tq==64: o = oq*16 + r16 -> val = net2_b[i*64 + o]
__global__ __launch_bounds__(256) void k_w2t(const float* __restrict__ w2, const float* __restrict__ b2,
                                             unsigned short* __restrict__ w2t){
  int u = blockIdx.x*blockDim.x + threadIdx.x;
  if (u >= W2T_ELEMS) return;
  int j = u & 7;
  int lane = (u >> 3) & 63;
  int kc = (u >> 9) & 1;
  int tg = u >> 10;            // 0..259
  int oq = tg / TPQ, tq = tg - oq*TPQ;
  int r16 = lane & 15, kg = lane >> 4;
  int i = kc*32 + kg*8 + j;
  float v;
  if (tq < 64) v = w2[(size_t)i*4096 + (oq*1024 + tq*16 + r16)];
  else         v = b2[i*64 + oq*16 + r16];
  w2t[u] = f2bf(v);
}

// generic transpose: T[c*R + r] = M[r*C + c]
__global__ __launch_bounds__(256) void k_tr(const float* __restrict__ m, float* __restrict__ t, int R, int C){
  int i = blockIdx.x*blockDim.x + threadIdx.x;
  if (i >= R*C) return;
  int r = i / C, c = i - r*C;
  t[c*R + r] = m[i];
}

// histograms: degS[src]++, degD[dst]++
__global__ __launch_bounds__(256) void k_hist(const int* __restrict__ src, const int* __restrict__ dst,
                                              int* __restrict__ degS, int* __restrict__ degD){
  int e = blockIdx.x*blockDim.x + threadIdx.x;
  if (e < NE){ atomicAdd(&degS[src[e]], 1); atomicAdd(&degD[dst[e]], 1); }
}
__global__ __launch_bounds__(256) void k_invd(const int* __restrict__ degD, float* __restrict__ d){
  int n = blockIdx.x*blockDim.x + threadIdx.x;
  if (n < NN) d[n] = degD[n] > 0 ? 1.f/(float)degD[n] : 0.f;
}

// single-block scan via wave shuffles: rowptr[0..NPAD] from deg[0..NPAD)
__global__ __launch_bounds__(1024) void k_scan(const int* __restrict__ deg, int* __restrict__ rowptr){
  __shared__ int wsum[16];
  __shared__ int base;
  int tid = threadIdx.x, lane = tid & 63, wv = tid >> 6;
  if (tid == 0){ base = 0; rowptr[0] = 0; }
  __syncthreads();
  for (int c0 = 0; c0 < NPAD; c0 += 1024){
    int i = c0 + tid;
    int v = (i < NPAD) ? deg[i] : 0;
    int s = v;
    #pragma unroll
    for (int off=1; off<64; off<<=1){
      int t = __shfl_up(s, off);
      if (lane >= off) s += t;
    }
    if (lane == 63) wsum[wv] = s;
    __syncthreads();
    if (wv == 0 && lane < 16){
      int ws = wsum[lane];
      #pragma unroll
      for (int off=1; off<16; off<<=1){
        int t = __shfl_up(ws, off);
        if (lane >= off) ws += t;
      }
      wsum[lane] = ws;
    }
    __syncthreads();
    int wbase = (wv == 0) ? 0 : wsum[wv-1];
    if (i < NPAD) rowptr[i+1] = base + wbase + s;
    __syncthreads();
    if (tid == 0) base += wsum[15];
    __syncthreads();
  }
}

// scatter: src-sorted position p gets original edge id; also dst-sorted position for p
__global__ __launch_bounds__(256) void k_scatter(const int* __restrict__ src, const int* __restrict__ dst,
                         const int* __restrict__ rowptr, int* __restrict__ cnt,
                         const int* __restrict__ rowptrD, int* __restrict__ cntD,
                         int* __restrict__ sEid, int* __restrict__ sDpos){
  int e = blockIdx.x*blockDim.x + threadIdx.x;
  if (e >= NE) return;
  int s = src[e], d = dst[e];
  int pos = rowptr[s] + atomicAdd(&cnt[s], 1);
  sEid[pos] = e;
  sDpos[pos] = rowptrD[d] + atomicAdd(&cntD[d], 1);
}

// e1 sorted: e1s[pos][k] = bf16(leaky(edge_attr[sEid[pos]] @ net1_w.T + net1_b))
__global__ __launch_bounds__(256) void k_e1s(const float* __restrict__ ea, const float* __restrict__ w,
                     const float* __restrict__ b, const int* __restrict__ sEid,
                     unsigned short* __restrict__ e1s){
  int t = blockIdx.x*blockDim.x + threadIdx.x;   // t = pos*64 + k
  if (t >= NE*DD) return;
  int pos = t >> 6, k = t & 63;
  int e = sEid[pos];
  float acc = b[k];
  #pragma unroll
  for (int a=0; a<4; ++a) acc += ea[e*4+a] * w[k*4+a];
  e1s[t] = f2bf(lk(acc));
}

// graph histogram for batch-CSR
__global__ __launch_bounds__(256) void k_ghist(const int* __restrict__ batch, int* __restrict__ ghist){
  int n = blockIdx.x*blockDim.x + threadIdx.x;
  if (n < NN) atomicAdd(&ghist[batch[n]], 1);
}
// scan over 512 graph counts (single block of 512)
__global__ __launch_bounds__(512) void k_gscan(const int* __restrict__ ghist, int* __restrict__ gptr){
  __shared__ int wsum[8];
  int tid = threadIdx.x, lane = tid & 63, wv = tid >> 6;
  int s = ghist[tid];
  #pragma unroll
  for (int off=1; off<64; off<<=1){
    int t = __shfl_up(s, off);
    if (lane >= off) s += t;
  }
  if (lane == 63) wsum[wv] = s;
  __syncthreads();
  if (wv == 0 && lane < 8){
    int ws = wsum[lane];
    #pragma unroll
    for (int off=1; off<8; off<<=1){
      int t = __shfl_up(ws, off);
      if (lane >= off) ws += t;
    }
    wsum[lane] = ws;
  }
  __syncthreads();
  if (tid == 0) gptr[0] = 0;
  int wbase = (wv == 0) ? 0 : wsum[wv-1];
  gptr[tid+1] = wbase + s;
}

// ---------- fused: block = (16-node block, o-quarter). A-quarter in LDS, then MFMA edge-GEMMs ----------
// Phase A (8 waves, 65 tiles): A[n][c] = sum_i w2t-tile * hbf[n][i], bf16 into LDS (XOR-swizzled).
// Phase B: wave wv handles nodes {wv, wv+8}: per 16-edge tile, 2 MFMA vs A-slice -> 16 o-outputs,
//   plain store into dst-sorted msgbuf (no atomics).
__global__ __launch_bounds__(512) void k_fused8(const unsigned short* __restrict__ w2t,
                                                const unsigned short* __restrict__ hbf,
                                                const unsigned short* __restrict__ e1s,
                                                const int* __restrict__ sDpos,
                                                const int* __restrict__ rowptr,
                                                float* __restrict__ msgbuf){
  extern __shared__ char smem[];
  int lane = threadIdx.x & 63;
  int wv   = threadIdx.x >> 6;           // 0..7
  int n0   = blockIdx.x * 16;
  int oq   = blockIdx.y;                 // 0..3
  int r16 = lane & 15, kg = lane >> 4;

  // persistent B-fragments: bf16 h rows of the 16 nodes (col = node r16)
  const unsigned short* hp = hbf + (size_t)(n0 + r16)*DD;
  bf8 bh0 = *(const bf8*)(hp + kg*8);
  bf8 bh1 = *(const bf8*)(hp + 32 + kg*8);

  // phase A: 65 tiles round-robin over 8 waves; fully-contiguous 1KB wave-loads
  {
    const unsigned short* wq = w2t + (size_t)oq*TPQ*1024;
    for (int tq = wv; tq < TPQ; tq += 8){
      const unsigned short* wp = wq + (size_t)tq*1024;
      bf8 a0 = *(const bf8*)(wp + lane*8);
      bf8 a1 = *(const bf8*)(wp + 512 + lane*8);
      f32x4 acc = {0.f,0.f,0.f,0.f};
      acc = __builtin_amdgcn_mfma_f32_16x16x32_bf16(a0, bh0, acc, 0,0,0);
      acc = __builtin_amdgcn_mfma_f32_16x16x32_bf16(a1, bh1, acc, 0,0,0);
      unsigned u0 = (unsigned)f2bf(acc[0]) | ((unsigned)f2bf(acc[1]) << 16);
      unsigned u1 = (unsigned)f2bf(acc[2]) | ((unsigned)f2bf(acc[3]) << 16);
      unsigned long long ull = (unsigned long long)u0 | ((unsigned long long)u1 << 32);
      if (tq < 64){
        int o_rel = tq >> 2;                              // 0..15
        int slot_lin = ((tq & 3) << 1) + (kg >> 1);       // k>>3
        int slot = slot_lin ^ (o_rel & 7) ^ ((r16 & 1) << 2);
        *(unsigned long long*)(smem + (size_t)r16*NSTRIDE + o_rel*128 + (slot<<4) + ((kg & 1)*8)) = ull;
      } else {
        // bias tile: b = kg*4+j, node r16
        *(unsigned long long*)(smem + (size_t)r16*NSTRIDE + 2048 + kg*8) = ull;
      }
    }
  }
  __syncthreads();

  // phase B: wave wv handles nodes wv and wv+8
  #pragma unroll
  for (int s = 0; s < 2; ++s){
    int nl = wv + 8*s;
    int node = n0 + nl;
    int estart = rowptr[node], eend = rowptr[node + 1];
    const char* ab = smem + (size_t)nl*NSTRIDE;
    int swzn = (nl & 1) << 2;
    // B-frags for this node's A-slice (col = o_rel = r16), loop-invariant
    int slot0 = (kg) ^ (r16 & 7) ^ swzn;
    int slot1 = (4 + kg) ^ (r16 & 7) ^ swzn;
    bf8 B0 = *(const bf8*)(ab + r16*128 + (slot0<<4));
    bf8 B1 = *(const bf8*)(ab + r16*128 + (slot1<<4));
    float bias = bf2f(*(const unsigned short*)(ab + 2048 + r16*2));
    for (int eg = estart; eg < eend; eg += 16){
      bf8 af0 = {0,0,0,0,0,0,0,0}, af1 = {0,0,0,0,0,0,0,0};
      int er = eg + r16;
      if (er < eend){
        af0 = *(const bf8*)(e1s + (size_t)er*DD + kg*8);
        af1 = *(const bf8*)(e1s + (size_t)er*DD + 32 + kg*8);
      }
      int ebase = eg + kg*4;
      int dp[4];
      #pragma unroll
      for (int j=0; j<4; ++j){
        int e = ebase + j;
        dp[j] = (e < eend) ? sDpos[e] : -1;
      }
      f32x4 acc = {0.f,0.f,0.f,0.f};
      acc = __builtin_amdgcn_mfma_f32_16x16x32_bf16(af0, B0, acc, 0,0,0);
      acc = __builtin_amdgcn_mfma_f32_16x16x32_bf16(af1, B1, acc, 0,0,0);
      #pragma unroll
      for (int j=0; j<4; ++j){
        if (dp[j] >= 0)
          msgbuf[(size_t)dp[j]*DD + oq*16 + r16] = acc[j] + bias;
      }
    }
  }
}

// ---------- fused dst-segment-sum + NNConv-root + GRU (also emits bf16 h) ----------
#define NB 8
__global__ __launch_bounds__(256) void k_gru(float* __restrict__ h, unsigned short* __restrict__ hbf,
                      const float* __restrict__ msgbuf, const int* __restrict__ rowptrD,
                      const float* __restrict__ invd,
                      const float* __restrict__ cr, const float* __restrict__ cb,
                      const float* __restrict__ wihT, const float* __restrict__ whhT,
                      const float* __restrict__ bih, const float* __restrict__ bhh){
  int wid = (blockIdx.x*blockDim.x + threadIdx.x) >> 6;
  int lane = threadIdx.x & 63;
  int nb0 = wid * NB;
  if (nb0 >= NN) return;
  int cnt = NN - nb0 < NB ? NN - nb0 : NB;

  float hreg[NB], mreg[NB], mac[NB];
  #pragma unroll
  for (int t=0; t<NB; ++t){ hreg[t] = (t<cnt) ? h[(size_t)(nb0+t)*DD + lane] : 0.f; mac[t]=0.f; }
  for (int i=0; i<DD; ++i){
    float crv = cr[i*DD + lane];
    #pragma unroll
    for (int t=0; t<NB; ++t) mac[t] += __shfl(hreg[t], i) * crv;
  }
  #pragma unroll
  for (int t=0; t<NB; ++t){
    if (t < cnt){
      float ms = 0.f;
      int pa = rowptrD[nb0+t], pb = rowptrD[nb0+t+1];
      for (int p=pa; p<pb; ++p) ms += msgbuf[(size_t)p*DD + lane];
      float id = invd[nb0+t];
      mreg[t] = lk(ms*id + mac[t] + cb[lane]);
    } else mreg[t] = 0.f;
  }
  float air[NB]={}, aiz[NB]={}, ain[NB]={}, ahr[NB]={}, ahz[NB]={}, ahn[NB]={};
  for (int i=0; i<DD; ++i){
    float w0 = wihT[i*192 + lane], w1 = wihT[i*192 + 64 + lane], w2 = wihT[i*192 + 128 + lane];
    float v0 = whhT[i*192 + lane], v1 = whhT[i*192 + 64 + lane], v2 = whhT[i*192 + 128 + lane];
    #pragma unroll
    for (int t=0; t<NB; ++t){
      float mi = __shfl(mreg[t], i), hi = __shfl(hreg[t], i);
      air[t] += mi*w0; aiz[t] += mi*w1; ain[t] += mi*w2;
      ahr[t] += hi*v0; ahz[t] += hi*v1; ahn[t] += hi*v2;
    }
  }
  float bi0 = bih[lane], bi1 = bih[64+lane], bi2 = bih[128+lane];
  float bh0 = bhh[lane], bh1 = bhh[64+lane], bh2 = bhh[128+lane];
  #pragma unroll
  for (int t=0; t<NB; ++t){
    if (t < cnt){
      float r = sg(air[t]+bi0 + ahr[t]+bh0);
      float z = sg(aiz[t]+bi1 + ahz[t]+bh1);
      float n = tanhf(ain[t]+bi2 + r*(ahn[t]+bh2));
      float nh = (1.f - z)*n + z*hreg[t];
      h[(size_t)(nb0+t)*DD + lane] = nh;
      hbf[(size_t)(nb0+t)*DD + lane] = f2bf(nh);
    }
  }
}

// ---------- heads ----------
__global__ __launch_bounds__(256) void k_jbond(const float* __restrict__ h, const int* __restrict__ idx,
                        const float* __restrict__ w1T, const float* __restrict__ b1,
                        const float* __restrict__ w2, const float* __restrict__ b2,
                        float* __restrict__ jtmp){
  int wid = (blockIdx.x*blockDim.x + threadIdx.x) >> 6;
  int lane = threadIdx.x & 63;
  if (wid >= NJ*2) return;
  int a = idx[wid];
  float f = h[(size_t)a*DD + lane];
  float acc = b1[lane];
  for (int i=0; i<DD; ++i) acc += __shfl(f, i) * w1T[i*DD + lane];
  float p = lk(acc) * w2[lane];
  #pragma unroll
  for (int off=32; off; off>>=1) p += __shfl_xor(p, off);
  if (lane == 0) jtmp[wid] = p + b2[0];
}
__global__ __launch_bounds__(256) void k_jmean(const float* __restrict__ jtmp, float* __restrict__ o){
  int j = blockIdx.x*blockDim.x + threadIdx.x;
  if (j < NJ) o[j] = 0.5f*(jtmp[2*j] + jtmp[2*j+1]);
}
__global__ __launch_bounds__(256) void k_stem1(const float* __restrict__ h, const int* __restrict__ idx,
                        const float* __restrict__ w1T, const float* __restrict__ b1,
                        float* __restrict__ st1){
  int wid = (blockIdx.x*blockDim.x + threadIdx.x) >> 6;
  int lane = threadIdx.x & 63;
  if (wid >= NS) return;
  int a = idx[wid];
  float f = h[(size_t)a*DD + lane];
  float acc = b1[lane];
  for (int i=0; i<DD; ++i) acc += __shfl(f, i) * w1T[i*DD + lane];
  st1[(size_t)wid*DD + lane] = lk(acc);
}
// w2T[k*NO + c] layout -> coalesced inner loop
__global__ __launch_bounds__(256) void k_stem2(const float* __restrict__ st1, const float* __restrict__ w2T,
                        const float* __restrict__ b2, float* __restrict__ o){
  int i = blockIdx.x*blockDim.x + threadIdx.x;
  if (i >= NS*NO) return;
  int r = i / NO, c = i - r*NO;
  float acc = b2[c];
  const float* t1 = st1 + (size_t)r*DD;
  for (int k=0; k<DD; ++k) acc += t1[k]*w2T[k*NO + c];
  o[i] = acc;
}

// ---------- Set2Set (1 step, zero init state) ----------
__global__ void k_qvec(const float* __restrict__ bih, const float* __restrict__ bhh, float* __restrict__ qv){
  int g = threadIdx.x;
  float gi = bih[g] + bhh[g];
  float gg = bih[128+g] + bhh[128+g];
  float go = bih[192+g] + bhh[192+g];
  float c = sg(gi)*tanhf(gg);
  qv[g] = sg(go)*tanhf(c);
}
__global__ __launch_bounds__(256) void k_e(const float* __restrict__ h, const float* __restrict__ qv,
                    const int* __restrict__ batch, float* __restrict__ evec, unsigned* __restrict__ emax){
  int n = (blockIdx.x*blockDim.x + threadIdx.x) >> 6;
  int lane = threadIdx.x & 63;
  if (n >= NN) return;
  float p = h[(size_t)n*DD + lane] * qv[lane];
  #pragma unroll
  for (int off=32; off; off>>=1) p += __shfl_xor(p, off);
  if (lane == 0){
    evec[n] = p;
    atomicMax(&emax[batch[n]], fenc(p));
  }
}
// wave per graph: rvec[g] = sum(ex_n * h_n) / sum(ex_n), single pass over batch-CSR
__global__ __launch_bounds__(256) void k_gsum(const float* __restrict__ h, const float* __restrict__ evec,
                       const unsigned* __restrict__ emax, const int* __restrict__ gptr,
                       float* __restrict__ rvec){
  int g = (blockIdx.x*blockDim.x + threadIdx.x) >> 6;
  int lane = threadIdx.x & 63;
  if (g >= NGG) return;
  int a = gptr[g], b = gptr[g+1];
  if (a >= b){ rvec[(size_t)g*DD + lane] = 0.f; return; }
  float m = fdec(emax[g]);
  float s = 0.f, vacc = 0.f;
  for (int n=a; n<b; ++n){
    float ex = expf(evec[n] - m);
    s += ex;
    vacc += ex * h[(size_t)n*DD + lane];
  }
  rvec[(size_t)g*DD + lane] = vacc / s;
}
__global__ __launch_bounds__(256) void k_gout(const float* __restrict__ qv, const float* __restrict__ rvec,
                       const float* __restrict__ lw, const float* __restrict__ lb, float* __restrict__ o){
  int t = blockIdx.x*blockDim.x + threadIdx.x;
  if (t >= NGG*2) return;
  int g = t >> 1, c = t & 1;
  float acc = lb[c];
  for (int j=0; j<DD; ++j) acc += qv[j]*lw[c*128 + j];
  for (int j=0; j<DD; ++j) acc += rvec[(size_t)g*DD + j]*lw[c*128 + 64 + j];
  o[g*2 + c] = acc;
}

// ---------- host ----------
extern "C" void kernel_launch(void* const* d_in, const int* in_sizes, int n_in,
                              void* d_out_, int out_size, void* d_ws, size_t ws_size,
                              hipStream_t stream){
  const float* x        = (const float*)d_in[0];
  const int*   ei       = (const int*)d_in[1];
  const float* eattr    = (const float*)d_in[2];
  const int*   jbidx    = (const int*)d_in[3];
  const int*   stidx    = (const int*)d_in[4];
  const int*   batch    = (const int*)d_in[5];
  const float* lin0_w   = (const float*)d_in[6];
  const float* lin0_b   = (const float*)d_in[7];
  const float* net1_w   = (const float*)d_in[8];
  const float* net1_b   = (const float*)d_in[9];
  const float* net2_w   = (const float*)d_in[10];
  const float* net2_b   = (const float*)d_in[11];
  const float* conv_root= (const float*)d_in[12];
  const float* conv_b   = (const float*)d_in[13];
  const float* gru_wih  = (const float*)d_in[14];
  const float* gru_whh  = (const float*)d_in[15];
  const float* gru_bih  = (const float*)d_in[16];
  const float* gru_bhh  = (const float*)d_in[17];
  const float* n2s_w1   = (const float*)d_in[18];
  const float* n2s_b1   = (const float*)d_in[19];
  const float* n2s_w2   = (const float*)d_in[20];
  const float* n2s_b2   = (const float*)d_in[21];
  const float* n2j_w1   = (const float*)d_in[22];
  const float* n2j_b1   = (const float*)d_in[23];
  const float* n2j_w2   = (const float*)d_in[24];
  const float* n2j_b2   = (const float*)d_in[25];
  const float* lstm_bih = (const float*)d_in[28];
  const float* lstm_bhh = (const float*)d_in[29];
  const float* lout_w   = (const float*)d_in[30];
  const float* lout_b   = (const float*)d_in[31];
  float* out = (float*)d_out_;

  const int* src = ei;
  const int* dst = ei + NE;

  char* ws = (char*)d_ws;
  size_t off = 0;
  auto alloc = [&](size_t bytes)->void*{
    void* p = ws + off; off = (off + bytes + 255) & ~(size_t)255; return p;
  };
  float* h    = (float*)alloc((size_t)NN*DD*4);
  float* msgbuf = (float*)alloc((size_t)NE*DD*4);
  unsigned short* hbf = (unsigned short*)alloc((size_t)NPAD*DD*2);
  unsigned short* e1s = (unsigned short*)alloc((size_t)NE*DD*2);
  unsigned short* w2t = (unsigned short*)alloc((size_t)W2T_ELEMS*2);
  // ---- zeroed group (one memset) ----
  int* degS   = (int*)alloc((size_t)NPAD*4);
  int* cnt    = (int*)alloc((size_t)NPAD*4);
  int* degD   = (int*)alloc((size_t)NPAD*4);
  int* cntD   = (int*)alloc((size_t)NPAD*4);
  int* ghist  = (int*)alloc((size_t)NGG*4);
  unsigned* emax = (unsigned*)alloc((size_t)NGG*4);   // end of zeroed group
  char* zend = ws + off;
  // ---- rest ----
  int* rowptr  = (int*)alloc((size_t)(NPAD+1)*4);
  int* rowptrD = (int*)alloc((size_t)(NPAD+1)*4);
  int* gptr    = (int*)alloc((size_t)(NGG+1)*4);
  int* sEid   = (int*)alloc((size_t)NE*4);
  int* sDpos  = (int*)alloc((size_t)NE*4);
  float* invd = (float*)alloc((size_t)NN*4);
  float* wihT = (float*)alloc((size_t)DD*192*4);
  float* whhT = (float*)alloc((size_t)DD*192*4);
  float* w1jT = (float*)alloc((size_t)DD*DD*4);
  float* w1sT = (float*)alloc((size_t)DD*DD*4);
  float* w2sT = (float*)alloc((size_t)DD*NO*4);
  float* evec = (float*)alloc((size_t)NN*4);
  float* rvec  = (float*)alloc((size_t)NGG*DD*4);
  float* qv    = (float*)alloc((size_t)DD*4);
  float* jtmp  = (float*)alloc((size_t)NJ*2*4);
  float* st1   = (float*)alloc((size_t)NS*DD*4);

  hipFuncSetAttribute((const void*)k_fused8, hipFuncAttributeMaxDynamicSharedMemorySize, LDSB);

  // ---- setup ----
  hipMemsetAsync(degS, 0, (size_t)(zend - (char*)degS), stream);  // degS,cnt,degD,cntD,ghist,emax
  k_lin0<<<(NPAD+3)/4, 256, 0, stream>>>(x, lin0_w, lin0_b, h, hbf);
  k_w2t<<<(W2T_ELEMS+255)/256, 256, 0, stream>>>(net2_w, net2_b, w2t);
  k_tr<<<48, 256, 0, stream>>>(gru_wih, wihT, 192, 64);
  k_tr<<<48, 256, 0, stream>>>(gru_whh, whhT, 192, 64);
  k_tr<<<16, 256, 0, stream>>>(n2j_w1, w1jT, 64, 64);
  k_tr<<<16, 256, 0, stream>>>(n2s_w1, w1sT, 64, 64);
  k_tr<<<27, 256, 0, stream>>>(n2s_w2, w2sT, NO, DD);
  // edge sorts (src-CSR and dst-CSR) + batch-CSR
  k_hist<<<391, 256, 0, stream>>>(src, dst, degS, degD);
  k_invd<<<98, 256, 0, stream>>>(degD, invd);
  k_scan<<<1, 1024, 0, stream>>>(degS, rowptr);
  k_scan<<<1, 1024, 0, stream>>>(degD, rowptrD);
  k_scatter<<<391, 256, 0, stream>>>(src, dst, rowptr, cnt, rowptrD, cntD, sEid, sDpos);
  k_e1s<<<25000, 256, 0, stream>>>(eattr, net1_w, net1_b, sEid, e1s);
  k_ghist<<<98, 256, 0, stream>>>(batch, ghist);
  k_gscan<<<1, 512, 0, stream>>>(ghist, gptr);

  // ---- 6 message-passing + GRU iterations (atomic-free) ----
  for (int it=0; it<6; ++it){
    k_fused8<<<dim3(NBLK, NQ), 512, LDSB, stream>>>(w2t, hbf, e1s, sDpos, rowptr, msgbuf);
    k_gru<<<782, 256, 0, stream>>>(h, hbf, msgbuf, rowptrD, invd, conv_root, conv_b, wihT, whhT, gru_bih, gru_bhh);
  }

  // ---- heads ----
  k_jbond<<<512, 256, 0, stream>>>(h, jbidx, w1jT, n2j_b1, n2j_w2, n2j_b2, jtmp);
  k_jmean<<<4, 256, 0, stream>>>(jtmp, out + NGG*2 + NS*NO);
  k_stem1<<<512, 256, 0, stream>>>(h, stidx, w1sT, n2s_b1, st1);
  k_stem2<<<840, 256, 0, stream>>>(st1, w2sT, n2s_b2, out + NGG*2);

  // ---- Set2Set ----
  k_qvec<<<1, 64, 0, stream>>>(lstm_bih, lstm_bhh, qv);
  k_e<<<6250, 256, 0, stream>>>(h, qv, batch, evec, emax);
  k_gsum<<<128, 256, 0, stream>>>(h, evec, emax, gptr, rvec);
  k_gout<<<4, 256, 0, stream>>>(qv, rvec, lout_w, lout_b, out);
}

// Round 8
// 691.577 us; speedup vs baseline: 2.3203x; 1.5106x over previous
//
#include <hip/hip_runtime.h>
#include <stdint.h>
#include <stddef.h>

#define NN 25000     // nodes
#define NPAD 25008   // 1563*16
#define NBLK 1563    // node blocks of 16
#define NE 100000    // edges
#define FEAT 16
#define DD 64
#define NGG 512
#define NJ 1024
#define NS 2048
#define NO 105
#define SLOPE 0.01f
#define NQ 4         // o-quarters
#define TPQ 65       // tiles per quarter: 64 W-tiles + 1 bias tile
#define W2T_ELEMS (NQ*TPQ*1024)   // 266240 bf16
#define NSTRIDE 2112 // bytes per node in LDS: 16 o-rows*128 + 32 bias + 32 pad
#define LDSB (16*NSTRIDE)         // 33792
#define WG_TILES 28  // gru packed tiles: 4 conv(cr^T) + 12 wih + 12 whh
#define WG_ELEMS (WG_TILES*1024)

typedef short bf8 __attribute__((ext_vector_type(8)));   // 8 bf16 raw bits (4 VGPR)
typedef float f32x4 __attribute__((ext_vector_type(4)));

__device__ __forceinline__ float lk(float v){ return v > 0.f ? v : SLOPE*v; }
__device__ __forceinline__ unsigned short f2bf(float f){
  unsigned int x = __float_as_uint(f);
  x += 0x7fffu + ((x>>16)&1u);           // round-to-nearest-even
  return (unsigned short)(x>>16);
}
__device__ __forceinline__ float bf2f(unsigned short u){ return __uint_as_float(((unsigned int)u)<<16); }
__device__ __forceinline__ float sg(float x){ return 1.f/(1.f+expf(-x)); }
__device__ __forceinline__ unsigned fenc(float f){ unsigned u = __float_as_uint(f); return (u & 0x80000000u) ? ~u : (u | 0x80000000u); }
__device__ __forceinline__ float fdec(unsigned k){ unsigned u = (k & 0x80000000u) ? (k ^ 0x80000000u) : ~k; return __uint_as_float(u); }

// ---------- setup kernels ----------

// out = leaky(x @ lin0_w.T + lin0_b); also writes bf16 copy; zero-fills hbf pad rows
__global__ __launch_bounds__(256) void k_lin0(const float* __restrict__ x, const float* __restrict__ w,
                       const float* __restrict__ b, float* __restrict__ h, unsigned short* __restrict__ hbf){
  int wid = (blockIdx.x*blockDim.x + threadIdx.x) >> 6;
  int lane = threadIdx.x & 63;
  if (wid >= NPAD) return;
  if (wid >= NN){ hbf[(size_t)wid*DD + lane] = 0; return; }
  float xv = lane < FEAT ? x[wid*FEAT + lane] : 0.f;
  float acc = b[lane];
  #pragma unroll
  for (int f=0; f<FEAT; ++f) acc += __shfl(xv, f) * w[lane*FEAT + f];
  float v = lk(acc);
  h[wid*DD + lane] = v;
  hbf[(size_t)wid*DD + lane] = f2bf(v);
}

// tile-major reordered W2 (+bias tile), bf16 (see round 7 comments)
__global__ __launch_bounds__(256) void k_w2t(const float* __restrict__ w2, const float* __restrict__ b2,
                                             unsigned short* __restrict__ w2t){
  int u = blockIdx.x*blockDim.x + threadIdx.x;
  if (u >= W2T_ELEMS) return;
  int j = u & 7;
  int lane = (u >> 3) & 63;
  int kc = (u >> 9) & 1;
  int tg = u >> 10;            // 0..259
  int oq = tg / TPQ, tq = tg - oq*TPQ;
  int r16 = lane & 15, kg = lane >> 4;
  int i = kc*32 + kg*8 + j;
  float v;
  if (tq < 64) v = w2[(size_t)i*4096 + (oq*1024 + tq*16 + r16)];
  else         v = b2[i*64 + oq*16 + r16];
  w2t[u] = f2bf(v);
}

// packed GRU weights, tile-major bf16: tiles 0..3 = cr^T (conv), 4..15 = wih rows, 16..27 = whh rows
__global__ __launch_bounds__(256) void k_wg(const float* __restrict__ cr, const float* __restrict__ wih,
                                            const float* __restrict__ whh, unsigned short* __restrict__ wgru){
  int u = blockIdx.x*blockDim.x + threadIdx.x;
  if (u >= WG_ELEMS) return;
  int j = u & 7;
  int lane = (u >> 3) & 63;
  int kc = (u >> 9) & 1;
  int t = u >> 10;             // 0..27
  int r16 = lane & 15, kg = lane >> 4;
  int i = kc*32 + kg*8 + j;
  float v;
  if (t < 4)       v = cr[(size_t)i*DD + t*16 + r16];            // B[o][i] = cr[i][o]
  else if (t < 16) v = wih[(size_t)((t-4)*16 + r16)*DD + i];     // B[o][i] = wih[o][i]
  else             v = whh[(size_t)((t-16)*16 + r16)*DD + i];
  wgru[u] = f2bf(v);
}

// generic transpose: T[c*R + r] = M[r*C + c]
__global__ __launch_bounds__(256) void k_tr(const float* __restrict__ m, float* __restrict__ t, int R, int C){
  int i = blockIdx.x*blockDim.x + threadIdx.x;
  if (i >= R*C) return;
  int r = i / C, c = i - r*C;
  t[c*R + r] = m[i];
}

// histograms: degS[src]++, degD[dst]++
__global__ __launch_bounds__(256) void k_hist(const int* __restrict__ src, const int* __restrict__ dst,
                                              int* __restrict__ degS, int* __restrict__ degD){
  int e = blockIdx.x*blockDim.x + threadIdx.x;
  if (e < NE){ atomicAdd(&degS[src[e]], 1); atomicAdd(&degD[dst[e]], 1); }
}
__global__ __launch_bounds__(256) void k_invd(const int* __restrict__ degD, float* __restrict__ d){
  int n = blockIdx.x*blockDim.x + threadIdx.x;
  if (n < NN) d[n] = degD[n] > 0 ? 1.f/(float)degD[n] : 0.f;
}

// single-block scan via wave shuffles: rowptr[0..NPAD] from deg[0..NPAD)
__global__ __launch_bounds__(1024) void k_scan(const int* __restrict__ deg, int* __restrict__ rowptr){
  __shared__ int wsum[16];
  __shared__ int base;
  int tid = threadIdx.x, lane = tid & 63, wv = tid >> 6;
  if (tid == 0){ base = 0; rowptr[0] = 0; }
  __syncthreads();
  for (int c0 = 0; c0 < NPAD; c0 += 1024){
    int i = c0 + tid;
    int v = (i < NPAD) ? deg[i] : 0;
    int s = v;
    #pragma unroll
    for (int off=1; off<64; off<<=1){
      int t = __shfl_up(s, off);
      if (lane >= off) s += t;
    }
    if (lane == 63) wsum[wv] = s;
    __syncthreads();
    if (wv == 0 && lane < 16){
      int ws = wsum[lane];
      #pragma unroll
      for (int off=1; off<16; off<<=1){
        int t = __shfl_up(ws, off);
        if (lane >= off) ws += t;
      }
      wsum[lane] = ws;
    }
    __syncthreads();
    int wbase = (wv == 0) ? 0 : wsum[wv-1];
    if (i < NPAD) rowptr[i+1] = base + wbase + s;
    __syncthreads();
    if (tid == 0) base += wsum[15];
    __syncthreads();
  }
}

// scatter: src-sorted position p gets original edge id; also dst-sorted position for p
__global__ __launch_bounds__(256) void k_scatter(const int* __restrict__ src, const int* __restrict__ dst,
                         const int* __restrict__ rowptr, int* __restrict__ cnt,
                         const int* __restrict__ rowptrD, int* __restrict__ cntD,
                         int* __restrict__ sEid, int* __restrict__ sDpos){
  int e = blockIdx.x*blockDim.x + threadIdx.x;
  if (e >= NE) return;
  int s = src[e], d = dst[e];
  int pos = rowptr[s] + atomicAdd(&cnt[s], 1);
  sEid[pos] = e;
  sDpos[pos] = rowptrD[d] + atomicAdd(&cntD[d], 1);
}

// e1 sorted: e1s[pos][k] = bf16(leaky(edge_attr[sEid[pos]] @ net1_w.T + net1_b))
__global__ __launch_bounds__(256) void k_e1s(const float* __restrict__ ea, const float* __restrict__ w,
                     const float* __restrict__ b, const int* __restrict__ sEid,
                     unsigned short* __restrict__ e1s){
  int t = blockIdx.x*blockDim.x + threadIdx.x;   // t = pos*64 + k
  if (t >= NE*DD) return;
  int pos = t >> 6, k = t & 63;
  int e = sEid[pos];
  float acc = b[k];
  #pragma unroll
  for (int a=0; a<4; ++a) acc += ea[e*4+a] * w[k*4+a];
  e1s[t] = f2bf(lk(acc));
}

// graph histogram for batch-CSR
__global__ __launch_bounds__(256) void k_ghist(const int* __restrict__ batch, int* __restrict__ ghist){
  int n = blockIdx.x*blockDim.x + threadIdx.x;
  if (n < NN) atomicAdd(&ghist[batch[n]], 1);
}
// scan over 512 graph counts (single block of 512)
__global__ __launch_bounds__(512) void k_gscan(const int* __restrict__ ghist, int* __restrict__ gptr){
  __shared__ int wsum[8];
  int tid = threadIdx.x, lane = tid & 63, wv = tid >> 6;
  int s = ghist[tid];
  #pragma unroll
  for (int off=1; off<64; off<<=1){
    int t = __shfl_up(s, off);
    if (lane >= off) s += t;
  }
  if (lane == 63) wsum[wv] = s;
  __syncthreads();
  if (wv == 0 && lane < 8){
    int ws = wsum[lane];
    #pragma unroll
    for (int off=1; off<8; off<<=1){
      int t = __shfl_up(ws, off);
      if (lane >= off) ws += t;
    }
    wsum[lane] = ws;
  }
  __syncthreads();
  if (tid == 0) gptr[0] = 0;
  int wbase = (wv == 0) ? 0 : wsum[wv-1];
  gptr[tid+1] = wbase + s;
}

// ---------- fused message kernel (round 7, unchanged) ----------
__global__ __launch_bounds__(512) void k_fused8(const unsigned short* __restrict__ w2t,
                                                const unsigned short* __restrict__ hbf,
                                                const unsigned short* __restrict__ e1s,
                                                const int* __restrict__ sDpos,
                                                const int* __restrict__ rowptr,
                                                float* __restrict__ msgbuf){
  extern __shared__ char smem[];
  int lane = threadIdx.x & 63;
  int wv   = threadIdx.x >> 6;           // 0..7
  int n0   = blockIdx.x * 16;
  int oq   = blockIdx.y;                 // 0..3
  int r16 = lane & 15, kg = lane >> 4;

  const unsigned short* hp = hbf + (size_t)(n0 + r16)*DD;
  bf8 bh0 = *(const bf8*)(hp + kg*8);
  bf8 bh1 = *(const bf8*)(hp + 32 + kg*8);

  {
    const unsigned short* wq = w2t + (size_t)oq*TPQ*1024;
    for (int tq = wv; tq < TPQ; tq += 8){
      const unsigned short* wp = wq + (size_t)tq*1024;
      bf8 a0 = *(const bf8*)(wp + lane*8);
      bf8 a1 = *(const bf8*)(wp + 512 + lane*8);
      f32x4 acc = {0.f,0.f,0.f,0.f};
      acc = __builtin_amdgcn_mfma_f32_16x16x32_bf16(a0, bh0, acc, 0,0,0);
      acc = __builtin_amdgcn_mfma_f32_16x16x32_bf16(a1, bh1, acc, 0,0,0);
      unsigned u0 = (unsigned)f2bf(acc[0]) | ((unsigned)f2bf(acc[1]) << 16);
      unsigned u1 = (unsigned)f2bf(acc[2]) | ((unsigned)f2bf(acc[3]) << 16);
      unsigned long long ull = (unsigned long long)u0 | ((unsigned long long)u1 << 32);
      if (tq < 64){
        int o_rel = tq >> 2;
        int slot_lin = ((tq & 3) << 1) + (kg >> 1);
        int slot = slot_lin ^ (o_rel & 7) ^ ((r16 & 1) << 2);
        *(unsigned long long*)(smem + (size_t)r16*NSTRIDE + o_rel*128 + (slot<<4) + ((kg & 1)*8)) = ull;
      } else {
        *(unsigned long long*)(smem + (size_t)r16*NSTRIDE + 2048 + kg*8) = ull;
      }
    }
  }
  __syncthreads();

  #pragma unroll
  for (int s = 0; s < 2; ++s){
    int nl = wv + 8*s;
    int node = n0 + nl;
    int estart = rowptr[node], eend = rowptr[node + 1];
    const char* ab = smem + (size_t)nl*NSTRIDE;
    int swzn = (nl & 1) << 2;
    int slot0 = (kg) ^ (r16 & 7) ^ swzn;
    int slot1 = (4 + kg) ^ (r16 & 7) ^ swzn;
    bf8 B0 = *(const bf8*)(ab + r16*128 + (slot0<<4));
    bf8 B1 = *(const bf8*)(ab + r16*128 + (slot1<<4));
    float bias = bf2f(*(const unsigned short*)(ab + 2048 + r16*2));
    for (int eg = estart; eg < eend; eg += 16){
      bf8 af0 = {0,0,0,0,0,0,0,0}, af1 = {0,0,0,0,0,0,0,0};
      int er = eg + r16;
      if (er < eend){
        af0 = *(const bf8*)(e1s + (size_t)er*DD + kg*8);
        af1 = *(const bf8*)(e1s + (size_t)er*DD + 32 + kg*8);
      }
      int ebase = eg + kg*4;
      int dp[4];
      #pragma unroll
      for (int j=0; j<4; ++j){
        int e = ebase + j;
        dp[j] = (e < eend) ? sDpos[e] : -1;
      }
      f32x4 acc = {0.f,0.f,0.f,0.f};
      acc = __builtin_amdgcn_mfma_f32_16x16x32_bf16(af0, B0, acc, 0,0,0);
      acc = __builtin_amdgcn_mfma_f32_16x16x32_bf16(af1, B1, acc, 0,0,0);
      #pragma unroll
      for (int j=0; j<4; ++j){
        if (dp[j] >= 0)
          msgbuf[(size_t)dp[j]*DD + oq*16 + r16] = acc[j] + bias;
      }
    }
  }
}

// ---------- MFMA GRU: block = 16 nodes, 4 waves ----------
// Phase 1: segment-sum msgbuf (dst-CSR) -> msum LDS (fp32, stride 68).
// Phase 2: conv = MFMA(hbf, cr^T tile w); m = lk(msum*invd + conv + cb) -> bf16 -> swizzled LDS mbf.
// Phase 3: wave w computes o-range [w*16,w*16+16) of all 6 gate blocks via 12 MFMAs; gate math; write h/hbf.
__global__ __launch_bounds__(256) void k_gru(float* __restrict__ h, unsigned short* __restrict__ hbf,
                      const float* __restrict__ msgbuf, const int* __restrict__ rowptrD,
                      const float* __restrict__ invd,
                      const unsigned short* __restrict__ wgru,
                      const float* __restrict__ cb,
                      const float* __restrict__ bih, const float* __restrict__ bhh){
  __shared__ float msum[16*68];
  __shared__ unsigned short mbf[16*64];
  __shared__ float iv[16];
  int tid = threadIdx.x;
  int lane = tid & 63, wv = tid >> 6;
  int n0 = blockIdx.x * 16;
  int r16 = lane & 15, kg = lane >> 4;

  // A-frags of h (bf16): row = node r16 (pad rows are zero)
  const unsigned short* hp = hbf + (size_t)(n0 + r16)*DD;
  bf8 af0 = *(const bf8*)(hp + kg*8);
  bf8 af1 = *(const bf8*)(hp + 32 + kg*8);

  // phase 1: segment sums
  if (tid < 16) iv[tid] = (n0 + tid < NN) ? invd[n0 + tid] : 0.f;
  #pragma unroll
  for (int q=0; q<4; ++q){
    int nl = wv*4 + q;
    int node = n0 + nl;
    float ms = 0.f;
    if (node < NN){
      int pa = rowptrD[node], pb = rowptrD[node+1];
      for (int p=pa; p<pb; ++p) ms += msgbuf[(size_t)p*DD + lane];
    }
    msum[nl*68 + lane] = ms;
  }
  __syncthreads();

  // phase 2: conv tile w + m computation
  int o = wv*16 + r16;
  {
    const unsigned short* tp = wgru + (size_t)wv*1024;
    bf8 bc0 = *(const bf8*)(tp + lane*8);
    bf8 bc1 = *(const bf8*)(tp + 512 + lane*8);
    f32x4 cacc = {0.f,0.f,0.f,0.f};
    cacc = __builtin_amdgcn_mfma_f32_16x16x32_bf16(af0, bc0, cacc, 0,0,0);
    cacc = __builtin_amdgcn_mfma_f32_16x16x32_bf16(af1, bc1, cacc, 0,0,0);
    float cbo = cb[o];
    int gi_gran = o >> 3;
    #pragma unroll
    for (int j=0; j<4; ++j){
      int nl = kg*4 + j;
      float mval = lk(msum[nl*68 + o]*iv[nl] + cacc[j] + cbo);
      int swz = gi_gran ^ (nl & 7);
      *(unsigned short*)((char*)mbf + nl*128 + (swz<<4) + (o&7)*2) = f2bf(mval);
    }
  }
  __syncthreads();

  // phase 3: gates
  // A-frags of m from swizzled LDS: granule kc*4+kg of node r16
  bf8 am0 = *(const bf8*)((char*)mbf + r16*128 + (((kg) ^ (r16 & 7))<<4));
  bf8 am1 = *(const bf8*)((char*)mbf + r16*128 + (((4 + kg) ^ (r16 & 7))<<4));

  f32x4 gi_r={0,0,0,0}, gi_z={0,0,0,0}, gi_n={0,0,0,0};
  f32x4 gh_r={0,0,0,0}, gh_z={0,0,0,0}, gh_n={0,0,0,0};
  {
    const unsigned short* t0 = wgru + (size_t)(4 + 0*4 + wv)*1024;
    const unsigned short* t1 = wgru + (size_t)(4 + 1*4 + wv)*1024;
    const unsigned short* t2 = wgru + (size_t)(4 + 2*4 + wv)*1024;
    const unsigned short* u0 = wgru + (size_t)(16 + 0*4 + wv)*1024;
    const unsigned short* u1 = wgru + (size_t)(16 + 1*4 + wv)*1024;
    const unsigned short* u2 = wgru + (size_t)(16 + 2*4 + wv)*1024;
    gi_r = __builtin_amdgcn_mfma_f32_16x16x32_bf16(am0, *(const bf8*)(t0 + lane*8), gi_r, 0,0,0);
    gi_r = __builtin_amdgcn_mfma_f32_16x16x32_bf16(am1, *(const bf8*)(t0 + 512 + lane*8), gi_r, 0,0,0);
    gi_z = __builtin_amdgcn_mfma_f32_16x16x32_bf16(am0, *(const bf8*)(t1 + lane*8), gi_z, 0,0,0);
    gi_z = __builtin_amdgcn_mfma_f32_16x16x32_bf16(am1, *(const bf8*)(t1 + 512 + lane*8), gi_z, 0,0,0);
    gi_n = __builtin_amdgcn_mfma_f32_16x16x32_bf16(am0, *(const bf8*)(t2 + lane*8), gi_n, 0,0,0);
    gi_n = __builtin_amdgcn_mfma_f32_16x16x32_bf16(am1, *(const bf8*)(t2 + 512 + lane*8), gi_n, 0,0,0);
    gh_r = __builtin_amdgcn_mfma_f32_16x16x32_bf16(af0, *(const bf8*)(u0 + lane*8), gh_r, 0,0,0);
    gh_r = __builtin_amdgcn_mfma_f32_16x16x32_bf16(af1, *(const bf8*)(u0 + 512 + lane*8), gh_r, 0,0,0);
    gh_z = __builtin_amdgcn_mfma_f32_16x16x32_bf16(af0, *(const bf8*)(u1 + lane*8), gh_z, 0,0,0);
    gh_z = __builtin_amdgcn_mfma_f32_16x16x32_bf16(af1, *(const bf8*)(u1 + 512 + lane*8), gh_z, 0,0,0);
    gh_n = __builtin_amdgcn_mfma_f32_16x16x32_bf16(af0, *(const bf8*)(u2 + lane*8), gh_n, 0,0,0);
    gh_n = __builtin_amdgcn_mfma_f32_16x16x32_bf16(af1, *(const bf8*)(u2 + 512 + lane*8), gh_n, 0,0,0);
  }
  float bi0 = bih[o], bi1 = bih[64+o], bi2 = bih[128+o];
  float bh0 = bhh[o], bh1 = bhh[64+o], bh2 = bhh[128+o];
  #pragma unroll
  for (int j=0; j<4; ++j){
    int node = n0 + kg*4 + j;
    if (node < NN){
      size_t idx = (size_t)node*DD + o;
      float hv = h[idx];
      float r = sg(gi_r[j] + bi0 + gh_r[j] + bh0);
      float z = sg(gi_z[j] + bi1 + gh_z[j] + bh1);
      float nn = tanhf(gi_n[j] + bi2 + r*(gh_n[j] + bh2));
      float nh = (1.f - z)*nn + z*hv;
      h[idx] = nh;
      hbf[idx] = f2bf(nh);
    }
  }
}

// ---------- heads ----------
__global__ __launch_bounds__(256) void k_jbond(const float* __restrict__ h, const int* __restrict__ idx,
                        const float* __restrict__ w1T, const float* __restrict__ b1,
                        const float* __restrict__ w2, const float* __restrict__ b2,
                        float* __restrict__ jtmp){
  int wid = (blockIdx.x*blockDim.x + threadIdx.x) >> 6;
  int lane = threadIdx.x & 63;
  if (wid >= NJ*2) return;
  int a = idx[wid];
  float f = h[(size_t)a*DD + lane];
  float acc = b1[lane];
  for (int i=0; i<DD; ++i) acc += __shfl(f, i) * w1T[i*DD + lane];
  float p = lk(acc) * w2[lane];
  #pragma unroll
  for (int off=32; off; off>>=1) p += __shfl_xor(p, off);
  if (lane == 0) jtmp[wid] = p + b2[0];
}
__global__ __launch_bounds__(256) void k_jmean(const float* __restrict__ jtmp, float* __restrict__ o){
  int j = blockIdx.x*blockDim.x + threadIdx.x;
  if (j < NJ) o[j] = 0.5f*(jtmp[2*j] + jtmp[2*j+1]);
}
__global__ __launch_bounds__(256) void k_stem1(const float* __restrict__ h, const int* __restrict__ idx,
                        const float* __restrict__ w1T, const float* __restrict__ b1,
                        float* __restrict__ st1){
  int wid = (blockIdx.x*blockDim.x + threadIdx.x) >> 6;
  int lane = threadIdx.x & 63;
  if (wid >= NS) return;
  int a = idx[wid];
  float f = h[(size_t)a*DD + lane];
  float acc = b1[lane];
  for (int i=0; i<DD; ++i) acc += __shfl(f, i) * w1T[i*DD + lane];
  st1[(size_t)wid*DD + lane] = lk(acc);
}
// w2T[k*NO + c] layout -> coalesced inner loop
__global__ __launch_bounds__(256) void k_stem2(const float* __restrict__ st1, const float* __restrict__ w2T,
                        const float* __restrict__ b2, float* __restrict__ o){
  int i = blockIdx.x*blockDim.x + threadIdx.x;
  if (i >= NS*NO) return;
  int r = i / NO, c = i - r*NO;
  float acc = b2[c];
  const float* t1 = st1 + (size_t)r*DD;
  for (int k=0; k<DD; ++k) acc += t1[k]*w2T[k*NO + c];
  o[i] = acc;
}

// ---------- Set2Set (1 step, zero init state) ----------
__global__ void k_qvec(const float* __restrict__ bih, const float* __restrict__ bhh, float* __restrict__ qv){
  int g = threadIdx.x;
  float gi = bih[g] + bhh[g];
  float gg = bih[128+g] + bhh[128+g];
  float go = bih[192+g] + bhh[192+g];
  float c = sg(gi)*tanhf(gg);
  qv[g] = sg(go)*tanhf(c);
}
__global__ __launch_bounds__(256) void k_e(const float* __restrict__ h, const float* __restrict__ qv,
                    const int* __restrict__ batch, float* __restrict__ evec, unsigned* __restrict__ emax){
  int n = (blockIdx.x*blockDim.x + threadIdx.x) >> 6;
  int lane = threadIdx.x & 63;
  if (n >= NN) return;
  float p = h[(size_t)n*DD + lane] * qv[lane];
  #pragma unroll
  for (int off=32; off; off>>=1) p += __shfl_xor(p, off);
  if (lane == 0){
    evec[n] = p;
    atomicMax(&emax[batch[n]], fenc(p));
  }
}
// wave per graph: rvec[g] = sum(ex_n * h_n) / sum(ex_n), single pass over batch-CSR
__global__ __launch_bounds__(256) void k_gsum(const float* __restrict__ h, const float* __restrict__ evec,
                       const unsigned* __restrict__ emax, const int* __restrict__ gptr,
                       float* __restrict__ rvec){
  int g = (blockIdx.x*blockDim.x + threadIdx.x) >> 6;
  int lane = threadIdx.x & 63;
  if (g >= NGG) return;
  int a = gptr[g], b = gptr[g+1];
  if (a >= b){ rvec[(size_t)g*DD + lane] = 0.f; return; }
  float m = fdec(emax[g]);
  float s = 0.f, vacc = 0.f;
  for (int n=a; n<b; ++n){
    float ex = expf(evec[n] - m);
    s += ex;
    vacc += ex * h[(size_t)n*DD + lane];
  }
  rvec[(size_t)g*DD + lane] = vacc / s;
}
__global__ __launch_bounds__(256) void k_gout(const float* __restrict__ qv, const float* __restrict__ rvec,
                       const float* __restrict__ lw, const float* __restrict__ lb, float* __restrict__ o){
  int t = blockIdx.x*blockDim.x + threadIdx.x;
  if (t >= NGG*2) return;
  int g = t >> 1, c = t & 1;
  float acc = lb[c];
  for (int j=0; j<DD; ++j) acc += qv[j]*lw[c*128 + j];
  for (int j=0; j<DD; ++j) acc += rvec[(size_t)g*DD + j]*lw[c*128 + 64 + j];
  o[g*2 + c] = acc;
}

// ---------- host ----------
extern "C" void kernel_launch(void* const* d_in, const int* in_sizes, int n_in,
                              void* d_out_, int out_size, void* d_ws, size_t ws_size,
                              hipStream_t stream){
  const float* x        = (const float*)d_in[0];
  const int*   ei       = (const int*)d_in[1];
  const float* eattr    = (const float*)d_in[2];
  const int*   jbidx    = (const int*)d_in[3];
  const int*   stidx    = (const int*)d_in[4];
  const int*   batch    = (const int*)d_in[5];
  const float* lin0_w   = (const float*)d_in[6];
  const float* lin0_b   = (const float*)d_in[7];
  const float* net1_w   = (const float*)d_in[8];
  const float* net1_b   = (const float*)d_in[9];
  const float* net2_w   = (const float*)d_in[10];
  const float* net2_b   = (const float*)d_in[11];
  const float* conv_root= (const float*)d_in[12];
  const float* conv_b   = (const float*)d_in[13];
  const float* gru_wih  = (const float*)d_in[14];
  const float* gru_whh  = (const float*)d_in[15];
  const float* gru_bih  = (const float*)d_in[16];
  const float* gru_bhh  = (const float*)d_in[17];
  const float* n2s_w1   = (const float*)d_in[18];
  const float* n2s_b1   = (const float*)d_in[19];
  const float* n2s_w2   = (const float*)d_in[20];
  const float* n2s_b2   = (const float*)d_in[21];
  const float* n2j_w1   = (const float*)d_in[22];
  const float* n2j_b1   = (const float*)d_in[23];
  const float* n2j_w2   = (const float*)d_in[24];
  const float* n2j_b2   = (const float*)d_in[25];
  const float* lstm_bih = (const float*)d_in[28];
  const float* lstm_bhh = (const float*)d_in[29];
  const float* lout_w   = (const float*)d_in[30];
  const float* lout_b   = (const float*)d_in[31];
  float* out = (float*)d_out_;

  const int* src = ei;
  const int* dst = ei + NE;

  char* ws = (char*)d_ws;
  size_t off = 0;
  auto alloc = [&](size_t bytes)->void*{
    void* p = ws + off; off = (off + bytes + 255) & ~(size_t)255; return p;
  };
  float* h    = (float*)alloc((size_t)NN*DD*4);
  float* msgbuf = (float*)alloc((size_t)NE*DD*4);
  unsigned short* hbf = (unsigned short*)alloc((size_t)NPAD*DD*2);
  unsigned short* e1s = (unsigned short*)alloc((size_t)NE*DD*2);
  unsigned short* w2t = (unsigned short*)alloc((size_t)W2T_ELEMS*2);
  unsigned short* wgru = (unsigned short*)alloc((size_t)WG_ELEMS*2);
  // ---- zeroed group (one memset) ----
  int* degS   = (int*)alloc((size_t)NPAD*4);
  int* cnt    = (int*)alloc((size_t)NPAD*4);
  int* degD   = (int*)alloc((size_t)NPAD*4);
  int* cntD   = (int*)alloc((size_t)NPAD*4);
  int* ghist  = (int*)alloc((size_t)NGG*4);
  unsigned* emax = (unsigned*)alloc((size_t)NGG*4);   // end of zeroed group
  char* zend = ws + off;
  // ---- rest ----
  int* rowptr  = (int*)alloc((size_t)(NPAD+1)*4);
  int* rowptrD = (int*)alloc((size_t)(NPAD+1)*4);
  int* gptr    = (int*)alloc((size_t)(NGG+1)*4);
  int* sEid   = (int*)alloc((size_t)NE*4);
  int* sDpos  = (int*)alloc((size_t)NE*4);
  float* invd = (float*)alloc((size_t)NN*4);
  float* w1jT = (float*)alloc((size_t)DD*DD*4);
  float* w1sT = (float*)alloc((size_t)DD*DD*4);
  float* w2sT = (float*)alloc((size_t)DD*NO*4);
  float* evec = (float*)alloc((size_t)NN*4);
  float* rvec  = (float*)alloc((size_t)NGG*DD*4);
  float* qv    = (float*)alloc((size_t)DD*4);
  float* jtmp  = (float*)alloc((size_t)NJ*2*4);
  float* st1   = (float*)alloc((size_t)NS*DD*4);

  hipFuncSetAttribute((const void*)k_fused8, hipFuncAttributeMaxDynamicSharedMemorySize, LDSB);

  // ---- setup ----
  hipMemsetAsync(degS, 0, (size_t)(zend - (char*)degS), stream);  // degS,cnt,degD,cntD,ghist,emax
  k_lin0<<<(NPAD+3)/4, 256, 0, stream>>>(x, lin0_w, lin0_b, h, hbf);
  k_w2t<<<(W2T_ELEMS+255)/256, 256, 0, stream>>>(net2_w, net2_b, w2t);
  k_wg<<<(WG_ELEMS+255)/256, 256, 0, stream>>>(conv_root, gru_wih, gru_whh, wgru);
  k_tr<<<16, 256, 0, stream>>>(n2j_w1, w1jT, 64, 64);
  k_tr<<<16, 256, 0, stream>>>(n2s_w1, w1sT, 64, 64);
  k_tr<<<27, 256, 0, stream>>>(n2s_w2, w2sT, NO, DD);
  // edge sorts (src-CSR and dst-CSR) + batch-CSR
  k_hist<<<391, 256, 0, stream>>>(src, dst, degS, degD);
  k_invd<<<98, 256, 0, stream>>>(degD, invd);
  k_scan<<<1, 1024, 0, stream>>>(degS, rowptr);
  k_scan<<<1, 1024, 0, stream>>>(degD, rowptrD);
  k_scatter<<<391, 256, 0, stream>>>(src, dst, rowptr, cnt, rowptrD, cntD, sEid, sDpos);
  k_e1s<<<25000, 256, 0, stream>>>(eattr, net1_w, net1_b, sEid, e1s);
  k_ghist<<<98, 256, 0, stream>>>(batch, ghist);
  k_gscan<<<1, 512, 0, stream>>>(ghist, gptr);

  // ---- 6 message-passing + GRU iterations (atomic-free) ----
  for (int it=0; it<6; ++it){
    k_fused8<<<dim3(NBLK, NQ), 512, LDSB, stream>>>(w2t, hbf, e1s, sDpos, rowptr, msgbuf);
    k_gru<<<NBLK, 256, 0, stream>>>(h, hbf, msgbuf, rowptrD, invd, wgru, conv_b, gru_bih, gru_bhh);
  }

  // ---- heads ----
  k_jbond<<<512, 256, 0, stream>>>(h, jbidx, w1jT, n2j_b1, n2j_w2, n2j_b2, jtmp);
  k_jmean<<<4, 256, 0, stream>>>(jtmp, out + NGG*2 + NS*NO);
  k_stem1<<<512, 256, 0, stream>>>(h, stidx, w1sT, n2s_b1, st1);
  k_stem2<<<840, 256, 0, stream>>>(st1, w2sT, n2s_b2, out + NGG*2);

  // ---- Set2Set ----
  k_qvec<<<1, 64, 0, stream>>>(lstm_bih, lstm_bhh, qv);
  k_e<<<6250, 256, 0, stream>>>(h, qv, batch, evec, emax);
  k_gsum<<<128, 256, 0, stream>>>(h, evec, emax, gptr, rvec);
  k_gout<<<4, 256, 0, stream>>>(qv, rvec, lout_w, lout_b, out);
}

// Round 10
// 657.267 us; speedup vs baseline: 2.4414x; 1.0522x over previous
//
#include <hip/hip_runtime.h>
#include <stdint.h>
#include <stddef.h>

#define NN 25000     // nodes
#define NPAD 25008   // 1563*16
#define NBLK 1563    // node blocks of 16
#define NE 100000    // edges
#define FEAT 16
#define DD 64
#define NGG 512
#define NJ 1024
#define NS 2048
#define NO 105
#define SLOPE 0.01f
#define NQ 4         // o-quarters
#define TPQ 65       // tiles per quarter: 64 W-tiles + 1 bias tile
#define W2T_ELEMS (NQ*TPQ*1024)   // 266240 bf16
#define NSTRIDE 2080 // bytes per node in LDS: 16 o-rows*128 + 32 bias; stride/8 ≡ 4 (mod 16) -> bank spread
#define LDSB (16*NSTRIDE)         // 33280
#define WG_TILES 28  // gru packed tiles: 4 conv(cr^T) + 12 wih + 12 whh
#define WG_ELEMS (WG_TILES*1024)
#define TOTBLK (NBLK*NQ)          // 6252

typedef short bf8 __attribute__((ext_vector_type(8)));   // 8 bf16 raw bits (4 VGPR)
typedef float f32x4 __attribute__((ext_vector_type(4)));

__device__ __forceinline__ float lk(float v){ return v > 0.f ? v : SLOPE*v; }
__device__ __forceinline__ unsigned short f2bf(float f){
  unsigned int x = __float_as_uint(f);
  x += 0x7fffu + ((x>>16)&1u);           // round-to-nearest-even
  return (unsigned short)(x>>16);
}
__device__ __forceinline__ float bf2f(unsigned short u){ return __uint_as_float(((unsigned int)u)<<16); }
__device__ __forceinline__ float sg(float x){ return 1.f/(1.f+expf(-x)); }
__device__ __forceinline__ unsigned fenc(float f){ unsigned u = __float_as_uint(f); return (u & 0x80000000u) ? ~u : (u | 0x80000000u); }
__device__ __forceinline__ float fdec(unsigned k){ unsigned u = (k & 0x80000000u) ? (k ^ 0x80000000u) : ~k; return __uint_as_float(u); }

// ---------- setup kernels ----------

// out = leaky(x @ lin0_w.T + lin0_b); also writes bf16 copy; zero-fills hbf pad rows
__global__ __launch_bounds__(256) void k_lin0(const float* __restrict__ x, const float* __restrict__ w,
                       const float* __restrict__ b, float* __restrict__ h, unsigned short* __restrict__ hbf){
  int wid = (blockIdx.x*blockDim.x + threadIdx.x) >> 6;
  int lane = threadIdx.x & 63;
  if (wid >= NPAD) return;
  if (wid >= NN){ hbf[(size_t)wid*DD + lane] = 0; return; }
  float xv = lane < FEAT ? x[wid*FEAT + lane] : 0.f;
  float acc = b[lane];
  #pragma unroll
  for (int f=0; f<FEAT; ++f) acc += __shfl(xv, f) * w[lane*FEAT + f];
  float v = lk(acc);
  h[wid*DD + lane] = v;
  hbf[(size_t)wid*DD + lane] = f2bf(v);
}

// tile-major reordered W2 (+bias tile), bf16
__global__ __launch_bounds__(256) void k_w2t(const float* __restrict__ w2, const float* __restrict__ b2,
                                             unsigned short* __restrict__ w2t){
  int u = blockIdx.x*blockDim.x + threadIdx.x;
  if (u >= W2T_ELEMS) return;
  int j = u & 7;
  int lane = (u >> 3) & 63;
  int kc = (u >> 9) & 1;
  int tg = u >> 10;            // 0..259
  int oq = tg / TPQ, tq = tg - oq*TPQ;
  int r16 = lane & 15, kg = lane >> 4;
  int i = kc*32 + kg*8 + j;
  float v;
  if (tq < 64) v = w2[(size_t)i*4096 + (oq*1024 + tq*16 + r16)];
  else         v = b2[i*64 + oq*16 + r16];
  w2t[u] = f2bf(v);
}

// packed GRU weights, tile-major bf16: tiles 0..3 = cr^T (conv), 4..15 = wih rows, 16..27 = whh rows
__global__ __launch_bounds__(256) void k_wg(const float* __restrict__ cr, const float* __restrict__ wih,
                                            const float* __restrict__ whh, unsigned short* __restrict__ wgru){
  int u = blockIdx.x*blockDim.x + threadIdx.x;
  if (u >= WG_ELEMS) return;
  int j = u & 7;
  int lane = (u >> 3) & 63;
  int kc = (u >> 9) & 1;
  int t = u >> 10;             // 0..27
  int r16 = lane & 15, kg = lane >> 4;
  int i = kc*32 + kg*8 + j;
  float v;
  if (t < 4)       v = cr[(size_t)i*DD + t*16 + r16];            // B[o][i] = cr[i][o]
  else if (t < 16) v = wih[(size_t)((t-4)*16 + r16)*DD + i];     // B[o][i] = wih[o][i]
  else             v = whh[(size_t)((t-16)*16 + r16)*DD + i];
  wgru[u] = f2bf(v);
}

// generic transpose: T[c*R + r] = M[r*C + c]
__global__ __launch_bounds__(256) void k_tr(const float* __restrict__ m, float* __restrict__ t, int R, int C){
  int i = blockIdx.x*blockDim.x + threadIdx.x;
  if (i >= R*C) return;
  int r = i / C, c = i - r*C;
  t[c*R + r] = m[i];
}

// histograms: degS[src]++, degD[dst]++
__global__ __launch_bounds__(256) void k_hist(const int* __restrict__ src, const int* __restrict__ dst,
                                              int* __restrict__ degS, int* __restrict__ degD){
  int e = blockIdx.x*blockDim.x + threadIdx.x;
  if (e < NE){ atomicAdd(&degS[src[e]], 1); atomicAdd(&degD[dst[e]], 1); }
}
__global__ __launch_bounds__(256) void k_invd(const int* __restrict__ degD, float* __restrict__ d){
  int n = blockIdx.x*blockDim.x + threadIdx.x;
  if (n < NN) d[n] = degD[n] > 0 ? 1.f/(float)degD[n] : 0.f;
}

// single-block scan via wave shuffles: rowptr[0..NPAD] from deg[0..NPAD)
__global__ __launch_bounds__(1024) void k_scan(const int* __restrict__ deg, int* __restrict__ rowptr){
  __shared__ int wsum[16];
  __shared__ int base;
  int tid = threadIdx.x, lane = tid & 63, wv = tid >> 6;
  if (tid == 0){ base = 0; rowptr[0] = 0; }
  __syncthreads();
  for (int c0 = 0; c0 < NPAD; c0 += 1024){
    int i = c0 + tid;
    int v = (i < NPAD) ? deg[i] : 0;
    int s = v;
    #pragma unroll
    for (int off=1; off<64; off<<=1){
      int t = __shfl_up(s, off);
      if (lane >= off) s += t;
    }
    if (lane == 63) wsum[wv] = s;
    __syncthreads();
    if (wv == 0 && lane < 16){
      int ws = wsum[lane];
      #pragma unroll
      for (int off=1; off<16; off<<=1){
        int t = __shfl_up(ws, off);
        if (lane >= off) ws += t;
      }
      wsum[lane] = ws;
    }
    __syncthreads();
    int wbase = (wv == 0) ? 0 : wsum[wv-1];
    if (i < NPAD) rowptr[i+1] = base + wbase + s;
    __syncthreads();
    if (tid == 0) base += wsum[15];
    __syncthreads();
  }
}

// scatter: src-sorted position p gets original edge id; also dst-sorted position for p
__global__ __launch_bounds__(256) void k_scatter(const int* __restrict__ src, const int* __restrict__ dst,
                         const int* __restrict__ rowptr, int* __restrict__ cnt,
                         const int* __restrict__ rowptrD, int* __restrict__ cntD,
                         int* __restrict__ sEid, int* __restrict__ sDpos){
  int e = blockIdx.x*blockDim.x + threadIdx.x;
  if (e >= NE) return;
  int s = src[e], d = dst[e];
  int pos = rowptr[s] + atomicAdd(&cnt[s], 1);
  sEid[pos] = e;
  sDpos[pos] = rowptrD[d] + atomicAdd(&cntD[d], 1);
}

// e1 sorted: e1s[pos][k] = bf16(leaky(edge_attr[sEid[pos]] @ net1_w.T + net1_b))
__global__ __launch_bounds__(256) void k_e1s(const float* __restrict__ ea, const float* __restrict__ w,
                     const float* __restrict__ b, const int* __restrict__ sEid,
                     unsigned short* __restrict__ e1s){
  int t = blockIdx.x*blockDim.x + threadIdx.x;   // t = pos*64 + k
  if (t >= NE*DD) return;
  int pos = t >> 6, k = t & 63;
  int e = sEid[pos];
  float acc = b[k];
  #pragma unroll
  for (int a=0; a<4; ++a) acc += ea[e*4+a] * w[k*4+a];
  e1s[t] = f2bf(lk(acc));
}

// graph histogram for batch-CSR
__global__ __launch_bounds__(256) void k_ghist(const int* __restrict__ batch, int* __restrict__ ghist){
  int n = blockIdx.x*blockDim.x + threadIdx.x;
  if (n < NN) atomicAdd(&ghist[batch[n]], 1);
}
// scan over 512 graph counts (single block of 512)
__global__ __launch_bounds__(512) void k_gscan(const int* __restrict__ ghist, int* __restrict__ gptr){
  __shared__ int wsum[8];
  int tid = threadIdx.x, lane = tid & 63, wv = tid >> 6;
  int s = ghist[tid];
  #pragma unroll
  for (int off=1; off<64; off<<=1){
    int t = __shfl_up(s, off);
    if (lane >= off) s += t;
  }
  if (lane == 63) wsum[wv] = s;
  __syncthreads();
  if (wv == 0 && lane < 8){
    int ws = wsum[lane];
    #pragma unroll
    for (int off=1; off<8; off<<=1){
      int t = __shfl_up(ws, off);
      if (lane >= off) ws += t;
    }
    wsum[lane] = ws;
  }
  __syncthreads();
  if (tid == 0) gptr[0] = 0;
  int wbase = (wv == 0) ? 0 : wsum[wv-1];
  gptr[tid+1] = wbase + s;
}

// ---------- fused message kernel ----------
// 1D grid of TOTBLK, XCD-bijective decode: xcd = bid&7 gets a contiguous g-range; the 4 o-quarters
// of each 16-node block are consecutive g -> same XCD L2 (e1s/hbf reuse).
// LDS slot swizzle: A[n][o][k] stored at byte n*2080 + o*128 + ((k>>3)^(o&7)^(n&7))*16 + ((k>>2)&1)*8
// -> phase-A b64 writes 2 lanes/bank (free), phase-B b128 reads at floor. (f2bf pack: proven RTNE path)
__global__ __launch_bounds__(512) void k_fused8(const unsigned short* __restrict__ w2t,
                                                const unsigned short* __restrict__ hbf,
                                                const unsigned short* __restrict__ e1s,
                                                const int* __restrict__ sDpos,
                                                const int* __restrict__ rowptr,
                                                float* __restrict__ msgbuf){
  extern __shared__ char smem[];
  int lane = threadIdx.x & 63;
  int wv   = threadIdx.x >> 6;           // 0..7
  // XCD-bijective decode (6252 = 4*782 + 4*781)
  int xcd = blockIdx.x & 7, q = blockIdx.x >> 3;
  int g = xcd*781 + (xcd < 4 ? xcd : 4) + q;
  int n0 = (g >> 2) * 16;
  int oq = g & 3;
  int r16 = lane & 15, kg = lane >> 4;

  const unsigned short* hp = hbf + (size_t)(n0 + r16)*DD;
  bf8 bh0 = *(const bf8*)(hp + kg*8);
  bf8 bh1 = *(const bf8*)(hp + 32 + kg*8);

  // phase A: 65 tiles round-robin over 8 waves; contiguous 1KB wave-loads of w2t
  {
    const unsigned short* wq = w2t + (size_t)oq*TPQ*1024;
    int nsw = r16 & 7;
    for (int tq = wv; tq < TPQ; tq += 8){
      const unsigned short* wp = wq + (size_t)tq*1024;
      bf8 a0 = *(const bf8*)(wp + lane*8);
      bf8 a1 = *(const bf8*)(wp + 512 + lane*8);
      f32x4 acc = {0.f,0.f,0.f,0.f};
      acc = __builtin_amdgcn_mfma_f32_16x16x32_bf16(a0, bh0, acc, 0,0,0);
      acc = __builtin_amdgcn_mfma_f32_16x16x32_bf16(a1, bh1, acc, 0,0,0);
      unsigned u0 = (unsigned)f2bf(acc[0]) | ((unsigned)f2bf(acc[1]) << 16);
      unsigned u1 = (unsigned)f2bf(acc[2]) | ((unsigned)f2bf(acc[3]) << 16);
      unsigned long long ull = (unsigned long long)u0 | ((unsigned long long)u1 << 32);
      if (tq < 64){
        int o_rel = tq >> 2;
        int s = ((tq & 3) << 1) + (kg >> 1);            // k>>3
        int slot = s ^ (o_rel & 7) ^ nsw;
        *(unsigned long long*)(smem + (size_t)r16*NSTRIDE + o_rel*128 + (slot<<4) + ((kg & 1)*8)) = ull;
      } else {
        *(unsigned long long*)(smem + (size_t)r16*NSTRIDE + 2048 + kg*8) = ull;
      }
    }
  }
  __syncthreads();

  // phase B: wave wv handles nodes wv and wv+8
  #pragma unroll
  for (int s2 = 0; s2 < 2; ++s2){
    int nl = wv + 8*s2;
    int node = n0 + nl;
    int estart = rowptr[node], eend = rowptr[node + 1];
    const char* ab = smem + (size_t)nl*NSTRIDE;
    int nsw = nl & 7;
    int slot0 = (kg) ^ (r16 & 7) ^ nsw;
    int slot1 = (4 + kg) ^ (r16 & 7) ^ nsw;
    bf8 B0 = *(const bf8*)(ab + r16*128 + (slot0<<4));
    bf8 B1 = *(const bf8*)(ab + r16*128 + (slot1<<4));
    float bias = bf2f(*(const unsigned short*)(ab + 2048 + r16*2));
    for (int eg = estart; eg < eend; eg += 16){
      bf8 af0 = {0,0,0,0,0,0,0,0}, af1 = {0,0,0,0,0,0,0,0};
      int er = eg + r16;
      if (er < eend){
        af0 = *(const bf8*)(e1s + (size_t)er*DD + kg*8);
        af1 = *(const bf8*)(e1s + (size_t)er*DD + 32 + kg*8);
      }
      int ebase = eg + kg*4;
      int dp[4];
      #pragma unroll
      for (int j=0; j<4; ++j){
        int e = ebase + j;
        dp[j] = (e < eend) ? sDpos[e] : -1;
      }
      f32x4 acc = {0.f,0.f,0.f,0.f};
      acc = __builtin_amdgcn_mfma_f32_16x16x32_bf16(af0, B0, acc, 0,0,0);
      acc = __builtin_amdgcn_mfma_f32_16x16x32_bf16(af1, B1, acc, 0,0,0);
      #pragma unroll
      for (int j=0; j<4; ++j){
        if (dp[j] >= 0)
          msgbuf[(size_t)dp[j]*DD + oq*16 + r16] = acc[j] + bias;
      }
    }
  }
}

// ---------- MFMA GRU: block = 16 nodes, 4 waves ----------
__global__ __launch_bounds__(256) void k_gru(float* __restrict__ h, unsigned short* __restrict__ hbf,
                      const float* __restrict__ msgbuf, const int* __restrict__ rowptrD,
                      const float* __restrict__ invd,
                      const unsigned short* __restrict__ wgru,
                      const float* __restrict__ cb,
                      const float* __restrict__ bih, const float* __restrict__ bhh){
  __shared__ float msum[16*68];
  __shared__ unsigned short mbf[16*64];
  __shared__ float iv[16];
  int tid = threadIdx.x;
  int lane = tid & 63, wv = tid >> 6;
  int n0 = blockIdx.x * 16;
  int r16 = lane & 15, kg = lane >> 4;

  const unsigned short* hp = hbf + (size_t)(n0 + r16)*DD;
  bf8 af0 = *(const bf8*)(hp + kg*8);
  bf8 af1 = *(const bf8*)(hp + 32 + kg*8);

  // phase 1: segment sums
  if (tid < 16) iv[tid] = (n0 + tid < NN) ? invd[n0 + tid] : 0.f;
  #pragma unroll
  for (int q=0; q<4; ++q){
    int nl = wv*4 + q;
    int node = n0 + nl;
    float ms = 0.f;
    if (node < NN){
      int pa = rowptrD[node], pb = rowptrD[node+1];
      for (int p=pa; p<pb; ++p) ms += msgbuf[(size_t)p*DD + lane];
    }
    msum[nl*68 + lane] = ms;
  }
  __syncthreads();

  // phase 2: conv tile + m computation
  int o = wv*16 + r16;
  {
    const unsigned short* tp = wgru + (size_t)wv*1024;
    bf8 bc0 = *(const bf8*)(tp + lane*8);
    bf8 bc1 = *(const bf8*)(tp + 512 + lane*8);
    f32x4 cacc = {0.f,0.f,0.f,0.f};
    cacc = __builtin_amdgcn_mfma_f32_16x16x32_bf16(af0, bc0, cacc, 0,0,0);
    cacc = __builtin_amdgcn_mfma_f32_16x16x32_bf16(af1, bc1, cacc, 0,0,0);
    float cbo = cb[o];
    int gi_gran = o >> 3;
    #pragma unroll
    for (int j=0; j<4; ++j){
      int nl = kg*4 + j;
      float mval = lk(msum[nl*68 + o]*iv[nl] + cacc[j] + cbo);
      int swz = gi_gran ^ (nl & 7);
      *(unsigned short*)((char*)mbf + nl*128 + (swz<<4) + (o&7)*2) = f2bf(mval);
    }
  }
  __syncthreads();

  // phase 3: gates
  bf8 am0 = *(const bf8*)((char*)mbf + r16*128 + (((kg) ^ (r16 & 7))<<4));
  bf8 am1 = *(const bf8*)((char*)mbf + r16*128 + (((4 + kg) ^ (r16 & 7))<<4));

  f32x4 gi_r={0,0,0,0}, gi_z={0,0,0,0}, gi_n={0,0,0,0};
  f32x4 gh_r={0,0,0,0}, gh_z={0,0,0,0}, gh_n={0,0,0,0};
  {
    const unsigned short* t0 = wgru + (size_t)(4 + 0*4 + wv)*1024;
    const unsigned short* t1 = wgru + (size_t)(4 + 1*4 + wv)*1024;
    const unsigned short* t2 = wgru + (size_t)(4 + 2*4 + wv)*1024;
    const unsigned short* u0 = wgru + (size_t)(16 + 0*4 + wv)*1024;
    const unsigned short* u1 = wgru + (size_t)(16 + 1*4 + wv)*1024;
    const unsigned short* u2 = wgru + (size_t)(16 + 2*4 + wv)*1024;
    gi_r = __builtin_amdgcn_mfma_f32_16x16x32_bf16(am0, *(const bf8*)(t0 + lane*8), gi_r, 0,0,0);
    gi_r = __builtin_amdgcn_mfma_f32_16x16x32_bf16(am1, *(const bf8*)(t0 + 512 + lane*8), gi_r, 0,0,0);
    gi_z = __builtin_amdgcn_mfma_f32_16x16x32_bf16(am0, *(const bf8*)(t1 + lane*8), gi_z, 0,0,0);
    gi_z = __builtin_amdgcn_mfma_f32_16x16x32_bf16(am1, *(const bf8*)(t1 + 512 + lane*8), gi_z, 0,0,0);
    gi_n = __builtin_amdgcn_mfma_f32_16x16x32_bf16(am0, *(const bf8*)(t2 + lane*8), gi_n, 0,0,0);
    gi_n = __builtin_amdgcn_mfma_f32_16x16x32_bf16(am1, *(const bf8*)(t2 + 512 + lane*8), gi_n, 0,0,0);
    gh_r = __builtin_amdgcn_mfma_f32_16x16x32_bf16(af0, *(const bf8*)(u0 + lane*8), gh_r, 0,0,0);
    gh_r = __builtin_amdgcn_mfma_f32_16x16x32_bf16(af1, *(const bf8*)(u0 + 512 + lane*8), gh_r, 0,0,0);
    gh_z = __builtin_amdgcn_mfma_f32_16x16x32_bf16(af0, *(const bf8*)(u1 + lane*8), gh_z, 0,0,0);
    gh_z = __builtin_amdgcn_mfma_f32_16x16x32_bf16(af1, *(const bf8*)(u1 + 512 + lane*8), gh_z, 0,0,0);
    gh_n = __builtin_amdgcn_mfma_f32_16x16x32_bf16(af0, *(const bf8*)(u2 + lane*8), gh_n, 0,0,0);
    gh_n = __builtin_amdgcn_mfma_f32_16x16x32_bf16(af1, *(const bf8*)(u2 + 512 + lane*8), gh_n, 0,0,0);
  }
  float bi0 = bih[o], bi1 = bih[64+o], bi2 = bih[128+o];
  float bh0 = bhh[o], bh1 = bhh[64+o], bh2 = bhh[128+o];
  #pragma unroll
  for (int j=0; j<4; ++j){
    int node = n0 + kg*4 + j;
    if (node < NN){
      size_t idx = (size_t)node*DD + o;
      float hv = h[idx];
      float r = sg(gi_r[j] + bi0 + gh_r[j] + bh0);
      float z = sg(gi_z[j] + bi1 + gh_z[j] + bh1);
      float nn = tanhf(gi_n[j] + bi2 + r*(gh_n[j] + bh2));
      float nh = (1.f - z)*nn + z*hv;
      h[idx] = nh;
      hbf[idx] = f2bf(nh);
    }
  }
}

// ---------- heads ----------
__global__ __launch_bounds__(256) void k_jbond(const float* __restrict__ h, const int* __restrict__ idx,
                        const float* __restrict__ w1T, const float* __restrict__ b1,
                        const float* __restrict__ w2, const float* __restrict__ b2,
                        float* __restrict__ jtmp){
  int wid = (blockIdx.x*blockDim.x + threadIdx.x) >> 6;
  int lane = threadIdx.x & 63;
  if (wid >= NJ*2) return;
  int a = idx[wid];
  float f = h[(size_t)a*DD + lane];
  float acc = b1[lane];
  for (int i=0; i<DD; ++i) acc += __shfl(f, i) * w1T[i*DD + lane];
  float p = lk(acc) * w2[lane];
  #pragma unroll
  for (int off=32; off; off>>=1) p += __shfl_xor(p, off);
  if (lane == 0) jtmp[wid] = p + b2[0];
}
__global__ __launch_bounds__(256) void k_jmean(const float* __restrict__ jtmp, float* __restrict__ o){
  int j = blockIdx.x*blockDim.x + threadIdx.x;
  if (j < NJ) o[j] = 0.5f*(jtmp[2*j] + jtmp[2*j+1]);
}
__global__ __launch_bounds__(256) void k_stem1(const float* __restrict__ h, const int* __restrict__ idx,
                        const float* __restrict__ w1T, const float* __restrict__ b1,
                        float* __restrict__ st1){
  int wid = (blockIdx.x*blockDim.x + threadIdx.x) >> 6;
  int lane = threadIdx.x & 63;
  if (wid >= NS) return;
  int a = idx[wid];
  float f = h[(size_t)a*DD + lane];
  float acc = b1[lane];
  for (int i=0; i<DD; ++i) acc += __shfl(f, i) * w1T[i*DD + lane];
  st1[(size_t)wid*DD + lane] = lk(acc);
}
// w2T[k*NO + c] layout -> coalesced inner loop
__global__ __launch_bounds__(256) void k_stem2(const float* __restrict__ st1, const float* __restrict__ w2T,
                        const float* __restrict__ b2, float* __restrict__ o){
  int i = blockIdx.x*blockDim.x + threadIdx.x;
  if (i >= NS*NO) return;
  int r = i / NO, c = i - r*NO;
  float acc = b2[c];
  const float* t1 = st1 + (size_t)r*DD;
  for (int k=0; k<DD; ++k) acc += t1[k]*w2T[k*NO + c];
  o[i] = acc;
}

// ---------- Set2Set (1 step, zero init state) ----------
__global__ void k_qvec(const float* __restrict__ bih, const float* __restrict__ bhh, float* __restrict__ qv){
  int g = threadIdx.x;
  float gi = bih[g] + bhh[g];
  float gg = bih[128+g] + bhh[128+g];
  float go = bih[192+g] + bhh[192+g];
  float c = sg(gi)*tanhf(gg);
  qv[g] = sg(go)*tanhf(c);
}
__global__ __launch_bounds__(256) void k_e(const float* __restrict__ h, const float* __restrict__ qv,
                    const int* __restrict__ batch, float* __restrict__ evec, unsigned* __restrict__ emax){
  int n = (blockIdx.x*blockDim.x + threadIdx.x) >> 6;
  int lane = threadIdx.x & 63;
  if (n >= NN) return;
  float p = h[(size_t)n*DD + lane] * qv[lane];
  #pragma unroll
  for (int off=32; off; off>>=1) p += __shfl_xor(p, off);
  if (lane == 0){
    evec[n] = p;
    atomicMax(&emax[batch[n]], fenc(p));
  }
}
// wave per graph: rvec[g] = sum(ex_n * h_n) / sum(ex_n), single pass over batch-CSR
__global__ __launch_bounds__(256) void k_gsum(const float* __restrict__ h, const float* __restrict__ evec,
                       const unsigned* __restrict__ emax, const int* __restrict__ gptr,
                       float* __restrict__ rvec){
  int g = (blockIdx.x*blockDim.x + threadIdx.x) >> 6;
  int lane = threadIdx.x & 63;
  if (g >= NGG) return;
  int a = gptr[g], b = gptr[g+1];
  if (a >= b){ rvec[(size_t)g*DD + lane] = 0.f; return; }
  float m = fdec(emax[g]);
  float s = 0.f, vacc = 0.f;
  for (int n=a; n<b; ++n){
    float ex = expf(evec[n] - m);
    s += ex;
    vacc += ex * h[(size_t)n*DD + lane];
  }
  rvec[(size_t)g*DD + lane] = vacc / s;
}
__global__ __launch_bounds__(256) void k_gout(const float* __restrict__ qv, const float* __restrict__ rvec,
                       const float* __restrict__ lw, const float* __restrict__ lb, float* __restrict__ o){
  int t = blockIdx.x*blockDim.x + threadIdx.x;
  if (t >= NGG*2) return;
  int g = t >> 1, c = t & 1;
  float acc = lb[c];
  for (int j=0; j<DD; ++j) acc += qv[j]*lw[c*128 + j];
  for (int j=0; j<DD; ++j) acc += rvec[(size_t)g*DD + j]*lw[c*128 + 64 + j];
  o[g*2 + c] = acc;
}

// ---------- host ----------
extern "C" void kernel_launch(void* const* d_in, const int* in_sizes, int n_in,
                              void* d_out_, int out_size, void* d_ws, size_t ws_size,
                              hipStream_t stream){
  const float* x        = (const float*)d_in[0];
  const int*   ei       = (const int*)d_in[1];
  const float* eattr    = (const float*)d_in[2];
  const int*   jbidx    = (const int*)d_in[3];
  const int*   stidx    = (const int*)d_in[4];
  const int*   batch    = (const int*)d_in[5];
  const float* lin0_w   = (const float*)d_in[6];
  const float* lin0_b   = (const float*)d_in[7];
  const float* net1_w   = (const float*)d_in[8];
  const float* net1_b   = (const float*)d_in[9];
  const float* net2_w   = (const float*)d_in[10];
  const float* net2_b   = (const float*)d_in[11];
  const float* conv_root= (const float*)d_in[12];
  const float* conv_b   = (const float*)d_in[13];
  const float* gru_wih  = (const float*)d_in[14];
  const float* gru_whh  = (const float*)d_in[15];
  const float* gru_bih  = (const float*)d_in[16];
  const float* gru_bhh  = (const float*)d_in[17];
  const float* n2s_w1   = (const float*)d_in[18];
  const float* n2s_b1   = (const float*)d_in[19];
  const float* n2s_w2   = (const float*)d_in[20];
  const float* n2s_b2   = (const float*)d_in[21];
  const float* n2j_w1   = (const float*)d_in[22];
  const float* n2j_b1   = (const float*)d_in[23];
  const float* n2j_w2   = (const float*)d_in[24];
  const float* n2j_b2   = (const float*)d_in[25];
  const float* lstm_bih = (const float*)d_in[28];
  const float* lstm_bhh = (const float*)d_in[29];
  const float* lout_w   = (const float*)d_in[30];
  const float* lout_b   = (const float*)d_in[31];
  float* out = (float*)d_out_;

  const int* src = ei;
  const int* dst = ei + NE;

  char* ws = (char*)d_ws;
  size_t off = 0;
  auto alloc = [&](size_t bytes)->void*{
    void* p = ws + off; off = (off + bytes + 255) & ~(size_t)255; return p;
  };
  float* h    = (float*)alloc((size_t)NN*DD*4);
  float* msgbuf = (float*)alloc((size_t)NE*DD*4);
  unsigned short* hbf = (unsigned short*)alloc((size_t)NPAD*DD*2);
  unsigned short* e1s = (unsigned short*)alloc((size_t)NE*DD*2);
  unsigned short* w2t = (unsigned short*)alloc((size_t)W2T_ELEMS*2);
  unsigned short* wgru = (unsigned short*)alloc((size_t)WG_ELEMS*2);
  // ---- zeroed group (one memset) ----
  int* degS   = (int*)alloc((size_t)NPAD*4);
  int* cnt    = (int*)alloc((size_t)NPAD*4);
  int* degD   = (int*)alloc((size_t)NPAD*4);
  int* cntD   = (int*)alloc((size_t)NPAD*4);
  int* ghist  = (int*)alloc((size_t)NGG*4);
  unsigned* emax = (unsigned*)alloc((size_t)NGG*4);   // end of zeroed group
  char* zend = ws + off;
  // ---- rest ----
  int* rowptr  = (int*)alloc((size_t)(NPAD+1)*4);
  int* rowptrD = (int*)alloc((size_t)(NPAD+1)*4);
  int* gptr    = (int*)alloc((size_t)(NGG+1)*4);
  int* sEid   = (int*)alloc((size_t)NE*4);
  int* sDpos  = (int*)alloc((size_t)NE*4);
  float* invd = (float*)alloc((size_t)NN*4);
  float* w1jT = (float*)alloc((size_t)DD*DD*4);
  float* w1sT = (float*)alloc((size_t)DD*DD*4);
  float* w2sT = (float*)alloc((size_t)DD*NO*4);
  float* evec = (float*)alloc((size_t)NN*4);
  float* rvec  = (float*)alloc((size_t)NGG*DD*4);
  float* qv    = (float*)alloc((size_t)DD*4);
  float* jtmp  = (float*)alloc((size_t)NJ*2*4);
  float* st1   = (float*)alloc((size_t)NS*DD*4);

  hipFuncSetAttribute((const void*)k_fused8, hipFuncAttributeMaxDynamicSharedMemorySize, LDSB);

  // ---- setup ----
  hipMemsetAsync(degS, 0, (size_t)(zend - (char*)degS), stream);  // degS,cnt,degD,cntD,ghist,emax
  k_lin0<<<(NPAD+3)/4, 256, 0, stream>>>(x, lin0_w, lin0_b, h, hbf);
  k_w2t<<<(W2T_ELEMS+255)/256, 256, 0, stream>>>(net2_w, net2_b, w2t);
  k_wg<<<(WG_ELEMS+255)/256, 256, 0, stream>>>(conv_root, gru_wih, gru_whh, wgru);
  k_tr<<<16, 256, 0, stream>>>(n2j_w1, w1jT, 64, 64);
  k_tr<<<16, 256, 0, stream>>>(n2s_w1, w1sT, 64, 64);
  k_tr<<<27, 256, 0, stream>>>(n2s_w2, w2sT, NO, DD);
  // edge sorts (src-CSR and dst-CSR) + batch-CSR
  k_hist<<<391, 256, 0, stream>>>(src, dst, degS, degD);
  k_invd<<<98, 256, 0, stream>>>(degD, invd);
  k_scan<<<1, 1024, 0, stream>>>(degS, rowptr);
  k_scan<<<1, 1024, 0, stream>>>(degD, rowptrD);
  k_scatter<<<391, 256, 0, stream>>>(src, dst, rowptr, cnt, rowptrD, cntD, sEid, sDpos);
  k_e1s<<<25000, 256, 0, stream>>>(eattr, net1_w, net1_b, sEid, e1s);
  k_ghist<<<98, 256, 0, stream>>>(batch, ghist);
  k_gscan<<<1, 512, 0, stream>>>(ghist, gptr);

  // ---- 6 message-passing + GRU iterations (atomic-free) ----
  for (int it=0; it<6; ++it){
    k_fused8<<<TOTBLK, 512, LDSB, stream>>>(w2t, hbf, e1s, sDpos, rowptr, msgbuf);
    k_gru<<<NBLK, 256, 0, stream>>>(h, hbf, msgbuf, rowptrD, invd, wgru, conv_b, gru_bih, gru_bhh);
  }

  // ---- heads ----
  k_jbond<<<512, 256, 0, stream>>>(h, jbidx, w1jT, n2j_b1, n2j_w2, n2j_b2, jtmp);
  k_jmean<<<4, 256, 0, stream>>>(jtmp, out + NGG*2 + NS*NO);
  k_stem1<<<512, 256, 0, stream>>>(h, stidx, w1sT, n2s_b1, st1);
  k_stem2<<<840, 256, 0, stream>>>(st1, w2sT, n2s_b2, out + NGG*2);

  // ---- Set2Set ----
  k_qvec<<<1, 64, 0, stream>>>(lstm_bih, lstm_bhh, qv);
  k_e<<<6250, 256, 0, stream>>>(h, qv, batch, evec, emax);
  k_gsum<<<128, 256, 0, stream>>>(h, evec, emax, gptr, rvec);
  k_gout<<<4, 256, 0, stream>>>(qv, rvec, lout_w, lout_b, out);
}

// Round 11
// 652.684 us; speedup vs baseline: 2.4586x; 1.0070x over previous
//
#include <hip/hip_runtime.h>
#include <hip/hip_bf16.h>
#include <stdint.h>
#include <stddef.h>

#define NN 25000     // nodes
#define NPAD 25008   // 1563*16
#define NBLK 1563    // node blocks of 16
#define NE 100000    // edges
#define FEAT 16
#define DD 64
#define NGG 512
#define NJ 1024
#define NS 2048
#define NO 105
#define SLOPE 0.01f
#define NQ 4         // o-quarters
#define TPQ 65       // tiles per quarter: 64 W-tiles + 1 bias tile
#define W2T_ELEMS (NQ*TPQ*1024)   // 266240 bf16
#define NSTRIDE 2080 // bytes per node in LDS: 16 o-rows*128 + 32 bias; stride/8 ≡ 4 (mod 16) -> bank spread
#define LDSB (16*NSTRIDE)         // 33280
#define WG_TILES 28  // gru packed tiles: 4 conv(cr^T) + 12 wih + 12 whh
#define WG_ELEMS (WG_TILES*1024)
#define TOTBLK (NBLK*NQ)          // 6252

typedef short bf8 __attribute__((ext_vector_type(8)));   // 8 bf16 raw bits (4 VGPR)
typedef float f32x4 __attribute__((ext_vector_type(4)));

__device__ __forceinline__ float lk(float v){ return v > 0.f ? v : SLOPE*v; }
// native bf16 cast: compiler emits v_cvt_pk_bf16_f32 (correct operand order, RTNE) — T12/m240 path.
// (hand-written asm for this was round-9's correctness bug; integer bit-twiddle was round-10's VALU hog)
__device__ __forceinline__ unsigned short f2bf(float f){
  __hip_bfloat16 b = __float2bfloat16(f);
  union { __hip_bfloat16 b; unsigned short u; } c; c.b = b; return c.u;
}
__device__ __forceinline__ float bf2f(unsigned short u){ return __uint_as_float(((unsigned int)u)<<16); }
__device__ __forceinline__ float sg(float x){ return 1.f/(1.f+expf(-x)); }
__device__ __forceinline__ unsigned fenc(float f){ unsigned u = __float_as_uint(f); return (u & 0x80000000u) ? ~u : (u | 0x80000000u); }
__device__ __forceinline__ float fdec(unsigned k){ unsigned u = (k & 0x80000000u) ? (k ^ 0x80000000u) : ~k; return __uint_as_float(u); }

// ---------- setup kernels ----------

// out = leaky(x @ lin0_w.T + lin0_b); also writes bf16 copy; zero-fills hbf pad rows
__global__ __launch_bounds__(256) void k_lin0(const float* __restrict__ x, const float* __restrict__ w,
                       const float* __restrict__ b, float* __restrict__ h, unsigned short* __restrict__ hbf){
  int wid = (blockIdx.x*blockDim.x + threadIdx.x) >> 6;
  int lane = threadIdx.x & 63;
  if (wid >= NPAD) return;
  if (wid >= NN){ hbf[(size_t)wid*DD + lane] = 0; return; }
  float xv = lane < FEAT ? x[wid*FEAT + lane] : 0.f;
  float acc = b[lane];
  #pragma unroll
  for (int f=0; f<FEAT; ++f) acc += __shfl(xv, f) * w[lane*FEAT + f];
  float v = lk(acc);
  h[wid*DD + lane] = v;
  hbf[(size_t)wid*DD + lane] = f2bf(v);
}

// tile-major reordered W2 (+bias tile), bf16
__global__ __launch_bounds__(256) void k_w2t(const float* __restrict__ w2, const float* __restrict__ b2,
                                             unsigned short* __restrict__ w2t){
  int u = blockIdx.x*blockDim.x + threadIdx.x;
  if (u >= W2T_ELEMS) return;
  int j = u & 7;
  int lane = (u >> 3) & 63;
  int kc = (u >> 9) & 1;
  int tg = u >> 10;            // 0..259
  int oq = tg / TPQ, tq = tg - oq*TPQ;
  int r16 = lane & 15, kg = lane >> 4;
  int i = kc*32 + kg*8 + j;
  float v;
  if (tq < 64) v = w2[(size_t)i*4096 + (oq*1024 + tq*16 + r16)];
  else         v = b2[i*64 + oq*16 + r16];
  w2t[u] = f2bf(v);
}

// packed GRU weights, tile-major bf16: tiles 0..3 = cr^T (conv), 4..15 = wih rows, 16..27 = whh rows
__global__ __launch_bounds__(256) void k_wg(const float* __restrict__ cr, const float* __restrict__ wih,
                                            const float* __restrict__ whh, unsigned short* __restrict__ wgru){
  int u = blockIdx.x*blockDim.x + threadIdx.x;
  if (u >= WG_ELEMS) return;
  int j = u & 7;
  int lane = (u >> 3) & 63;
  int kc = (u >> 9) & 1;
  int t = u >> 10;             // 0..27
  int r16 = lane & 15, kg = lane >> 4;
  int i = kc*32 + kg*8 + j;
  float v;
  if (t < 4)       v = cr[(size_t)i*DD + t*16 + r16];            // B[o][i] = cr[i][o]
  else if (t < 16) v = wih[(size_t)((t-4)*16 + r16)*DD + i];     // B[o][i] = wih[o][i]
  else             v = whh[(size_t)((t-16)*16 + r16)*DD + i];
  wgru[u] = f2bf(v);
}

// generic transpose: T[c*R + r] = M[r*C + c]
__global__ __launch_bounds__(256) void k_tr(const float* __restrict__ m, float* __restrict__ t, int R, int C){
  int i = blockIdx.x*blockDim.x + threadIdx.x;
  if (i >= R*C) return;
  int r = i / C, c = i - r*C;
  t[c*R + r] = m[i];
}

// histograms: degS[src]++, degD[dst]++
__global__ __launch_bounds__(256) void k_hist(const int* __restrict__ src, const int* __restrict__ dst,
                                              int* __restrict__ degS, int* __restrict__ degD){
  int e = blockIdx.x*blockDim.x + threadIdx.x;
  if (e < NE){ atomicAdd(&degS[src[e]], 1); atomicAdd(&degD[dst[e]], 1); }
}
__global__ __launch_bounds__(256) void k_invd(const int* __restrict__ degD, float* __restrict__ d){
  int n = blockIdx.x*blockDim.x + threadIdx.x;
  if (n < NN) d[n] = degD[n] > 0 ? 1.f/(float)degD[n] : 0.f;
}

// single-block scan via wave shuffles: rowptr[0..NPAD] from deg[0..NPAD)
__global__ __launch_bounds__(1024) void k_scan(const int* __restrict__ deg, int* __restrict__ rowptr){
  __shared__ int wsum[16];
  __shared__ int base;
  int tid = threadIdx.x, lane = tid & 63, wv = tid >> 6;
  if (tid == 0){ base = 0; rowptr[0] = 0; }
  __syncthreads();
  for (int c0 = 0; c0 < NPAD; c0 += 1024){
    int i = c0 + tid;
    int v = (i < NPAD) ? deg[i] : 0;
    int s = v;
    #pragma unroll
    for (int off=1; off<64; off<<=1){
      int t = __shfl_up(s, off);
      if (lane >= off) s += t;
    }
    if (lane == 63) wsum[wv] = s;
    __syncthreads();
    if (wv == 0 && lane < 16){
      int ws = wsum[lane];
      #pragma unroll
      for (int off=1; off<16; off<<=1){
        int t = __shfl_up(ws, off);
        if (lane >= off) ws += t;
      }
      wsum[lane] = ws;
    }
    __syncthreads();
    int wbase = (wv == 0) ? 0 : wsum[wv-1];
    if (i < NPAD) rowptr[i+1] = base + wbase + s;
    __syncthreads();
    if (tid == 0) base += wsum[15];
    __syncthreads();
  }
}

// scatter: src-sorted position p gets original edge id; also dst-sorted position for p
__global__ __launch_bounds__(256) void k_scatter(const int* __restrict__ src, const int* __restrict__ dst,
                         const int* __restrict__ rowptr, int* __restrict__ cnt,
                         const int* __restrict__ rowptrD, int* __restrict__ cntD,
                         int* __restrict__ sEid, int* __restrict__ sDpos){
  int e = blockIdx.x*blockDim.x + threadIdx.x;
  if (e >= NE) return;
  int s = src[e], d = dst[e];
  int pos = rowptr[s] + atomicAdd(&cnt[s], 1);
  sEid[pos] = e;
  sDpos[pos] = rowptrD[d] + atomicAdd(&cntD[d], 1);
}

// e1 sorted: e1s[pos][k] = bf16(leaky(edge_attr[sEid[pos]] @ net1_w.T + net1_b))
__global__ __launch_bounds__(256) void k_e1s(const float* __restrict__ ea, const float* __restrict__ w,
                     const float* __restrict__ b, const int* __restrict__ sEid,
                     unsigned short* __restrict__ e1s){
  int t = blockIdx.x*blockDim.x + threadIdx.x;   // t = pos*64 + k
  if (t >= NE*DD) return;
  int pos = t >> 6, k = t & 63;
  int e = sEid[pos];
  float acc = b[k];
  #pragma unroll
  for (int a=0; a<4; ++a) acc += ea[e*4+a] * w[k*4+a];
  e1s[t] = f2bf(lk(acc));
}

// graph histogram for batch-CSR
__global__ __launch_bounds__(256) void k_ghist(const int* __restrict__ batch, int* __restrict__ ghist){
  int n = blockIdx.x*blockDim.x + threadIdx.x;
  if (n < NN) atomicAdd(&ghist[batch[n]], 1);
}
// scan over 512 graph counts (single block of 512)
__global__ __launch_bounds__(512) void k_gscan(const int* __restrict__ ghist, int* __restrict__ gptr){
  __shared__ int wsum[8];
  int tid = threadIdx.x, lane = tid & 63, wv = tid >> 6;
  int s = ghist[tid];
  #pragma unroll
  for (int off=1; off<64; off<<=1){
    int t = __shfl_up(s, off);
    if (lane >= off) s += t;
  }
  if (lane == 63) wsum[wv] = s;
  __syncthreads();
  if (wv == 0 && lane < 8){
    int ws = wsum[lane];
    #pragma unroll
    for (int off=1; off<8; off<<=1){
      int t = __shfl_up(ws, off);
      if (lane >= off) ws += t;
    }
    wsum[lane] = ws;
  }
  __syncthreads();
  if (tid == 0) gptr[0] = 0;
  int wbase = (wv == 0) ? 0 : wsum[wv-1];
  gptr[tid+1] = wbase + s;
}

// ---------- fused message kernel ----------
// 1D grid of TOTBLK, XCD-bijective decode: xcd = bid&7 gets a contiguous g-range; the 4 o-quarters
// of each 16-node block are consecutive g -> same XCD L2 (e1s/hbf reuse).
// LDS slot swizzle: A[n][o][k] stored at byte n*2080 + o*128 + ((k>>3)^(o&7)^(n&7))*16 + ((k>>2)&1)*8
// -> phase-A b64 writes 2 lanes/bank (free), phase-B b128 reads at floor.
__global__ __launch_bounds__(512) void k_fused8(const unsigned short* __restrict__ w2t,
                                                const unsigned short* __restrict__ hbf,
                                                const unsigned short* __restrict__ e1s,
                                                const int* __restrict__ sDpos,
                                                const int* __restrict__ rowptr,
                                                float* __restrict__ msgbuf){
  extern __shared__ char smem[];
  int lane = threadIdx.x & 63;
  int wv   = threadIdx.x >> 6;           // 0..7
  // XCD-bijective decode (6252 = 4*782 + 4*781)
  int xcd = blockIdx.x & 7, q = blockIdx.x >> 3;
  int g = xcd*781 + (xcd < 4 ? xcd : 4) + q;
  int n0 = (g >> 2) * 16;
  int oq = g & 3;
  int r16 = lane & 15, kg = lane >> 4;

  const unsigned short* hp = hbf + (size_t)(n0 + r16)*DD;
  bf8 bh0 = *(const bf8*)(hp + kg*8);
  bf8 bh1 = *(const bf8*)(hp + 32 + kg*8);

  // phase A: 65 tiles round-robin over 8 waves; contiguous 1KB wave-loads of w2t
  {
    const unsigned short* wq = w2t + (size_t)oq*TPQ*1024;
    int nsw = r16 & 7;
    for (int tq = wv; tq < TPQ; tq += 8){
      const unsigned short* wp = wq + (size_t)tq*1024;
      bf8 a0 = *(const bf8*)(wp + lane*8);
      bf8 a1 = *(const bf8*)(wp + 512 + lane*8);
      f32x4 acc = {0.f,0.f,0.f,0.f};
      acc = __builtin_amdgcn_mfma_f32_16x16x32_bf16(a0, bh0, acc, 0,0,0);
      acc = __builtin_amdgcn_mfma_f32_16x16x32_bf16(a1, bh1, acc, 0,0,0);
      unsigned u0 = (unsigned)f2bf(acc[0]) | ((unsigned)f2bf(acc[1]) << 16);
      unsigned u1 = (unsigned)f2bf(acc[2]) | ((unsigned)f2bf(acc[3]) << 16);
      unsigned long long ull = (unsigned long long)u0 | ((unsigned long long)u1 << 32);
      if (tq < 64){
        int o_rel = tq >> 2;
        int s = ((tq & 3) << 1) + (kg >> 1);            // k>>3
        int slot = s ^ (o_rel & 7) ^ nsw;
        *(unsigned long long*)(smem + (size_t)r16*NSTRIDE + o_rel*128 + (slot<<4) + ((kg & 1)*8)) = ull;
      } else {
        *(unsigned long long*)(smem + (size_t)r16*NSTRIDE + 2048 + kg*8) = ull;
      }
    }
  }
  __syncthreads();

  // phase B: wave wv handles nodes wv and wv+8
  #pragma unroll
  for (int s2 = 0; s2 < 2; ++s2){
    int nl = wv + 8*s2;
    int node = n0 + nl;
    int estart = rowptr[node], eend = rowptr[node + 1];
    const char* ab = smem + (size_t)nl*NSTRIDE;
    int nsw = nl & 7;
    int slot0 = (kg) ^ (r16 & 7) ^ nsw;
    int slot1 = (4 + kg) ^ (r16 & 7) ^ nsw;
    bf8 B0 = *(const bf8*)(ab + r16*128 + (slot0<<4));
    bf8 B1 = *(const bf8*)(ab + r16*128 + (slot1<<4));
    float bias = bf2f(*(const unsigned short*)(ab + 2048 + r16*2));
    for (int eg = estart; eg < eend; eg += 16){
      bf8 af0 = {0,0,0,0,0,0,0,0}, af1 = {0,0,0,0,0,0,0,0};
      int er = eg + r16;
      if (er < eend){
        af0 = *(const bf8*)(e1s + (size_t)er*DD + kg*8);
        af1 = *(const bf8*)(e1s + (size_t)er*DD + 32 + kg*8);
      }
      int ebase = eg + kg*4;
      int dp[4];
      #pragma unroll
      for (int j=0; j<4; ++j){
        int e = ebase + j;
        dp[j] = (e < eend) ? sDpos[e] : -1;
      }
      f32x4 acc = {0.f,0.f,0.f,0.f};
      acc = __builtin_amdgcn_mfma_f32_16x16x32_bf16(af0, B0, acc, 0,0,0);
      acc = __builtin_amdgcn_mfma_f32_16x16x32_bf16(af1, B1, acc, 0,0,0);
      #pragma unroll
      for (int j=0; j<4; ++j){
        if (dp[j] >= 0)
          msgbuf[(size_t)dp[j]*DD + oq*16 + r16] = acc[j] + bias;
      }
    }
  }
}

// ---------- MFMA GRU: block = 16 nodes, 4 waves ----------
__global__ __launch_bounds__(256) void k_gru(float* __restrict__ h, unsigned short* __restrict__ hbf,
                      const float* __restrict__ msgbuf, const int* __restrict__ rowptrD,
                      const float* __restrict__ invd,
                      const unsigned short* __restrict__ wgru,
                      const float* __restrict__ cb,
                      const float* __restrict__ bih, const float* __restrict__ bhh){
  __shared__ float msum[16*68];
  __shared__ unsigned short mbf[16*64];
  __shared__ float iv[16];
  int tid = threadIdx.x;
  int lane = tid & 63, wv = tid >> 6;
  int n0 = blockIdx.x * 16;
  int r16 = lane & 15, kg = lane >> 4;

  const unsigned short* hp = hbf + (size_t)(n0 + r16)*DD;
  bf8 af0 = *(const bf8*)(hp + kg*8);
  bf8 af1 = *(const bf8*)(hp + 32 + kg*8);

  // phase 1: segment sums
  if (tid < 16) iv[tid] = (n0 + tid < NN) ? invd[n0 + tid] : 0.f;
  #pragma unroll
  for (int q=0; q<4; ++q){
    int nl = wv*4 + q;
    int node = n0 + nl;
    float ms = 0.f;
    if (node < NN){
      int pa = rowptrD[node], pb = rowptrD[node+1];
      for (int p=pa; p<pb; ++p) ms += msgbuf[(size_t)p*DD + lane];
    }
    msum[nl*68 + lane] = ms;
  }
  __syncthreads();

  // phase 2: conv tile + m computation
  int o = wv*16 + r16;
  {
    const unsigned short* tp = wgru + (size_t)wv*1024;
    bf8 bc0 = *(const bf8*)(tp + lane*8);
    bf8 bc1 = *(const bf8*)(tp + 512 + lane*8);
    f32x4 cacc = {0.f,0.f,0.f,0.f};
    cacc = __builtin_amdgcn_mfma_f32_16x16x32_bf16(af0, bc0, cacc, 0,0,0);
    cacc = __builtin_amdgcn_mfma_f32_16x16x32_bf16(af1, bc1, cacc, 0,0,0);
    float cbo = cb[o];
    int gi_gran = o >> 3;
    #pragma unroll
    for (int j=0; j<4; ++j){
      int nl = kg*4 + j;
      float mval = lk(msum[nl*68 + o]*iv[nl] + cacc[j] + cbo);
      int swz = gi_gran ^ (nl & 7);
      *(unsigned short*)((char*)mbf + nl*128 + (swz<<4) + (o&7)*2) = f2bf(mval);
    }
  }
  __syncthreads();

  // phase 3: gates
  bf8 am0 = *(const bf8*)((char*)mbf + r16*128 + (((kg) ^ (r16 & 7))<<4));
  bf8 am1 = *(const bf8*)((char*)mbf + r16*128 + (((4 + kg) ^ (r16 & 7))<<4));

  f32x4 gi_r={0,0,0,0}, gi_z={0,0,0,0}, gi_n={0,0,0,0};
  f32x4 gh_r={0,0,0,0}, gh_z={0,0,0,0}, gh_n={0,0,0,0};
  {
    const unsigned short* t0 = wgru + (size_t)(4 + 0*4 + wv)*1024;
    const unsigned short* t1 = wgru + (size_t)(4 + 1*4 + wv)*1024;
    const unsigned short* t2 = wgru + (size_t)(4 + 2*4 + wv)*1024;
    const unsigned short* u0 = wgru + (size_t)(16 + 0*4 + wv)*1024;
    const unsigned short* u1 = wgru + (size_t)(16 + 1*4 + wv)*1024;
    const unsigned short* u2 = wgru + (size_t)(16 + 2*4 + wv)*1024;
    gi_r = __builtin_amdgcn_mfma_f32_16x16x32_bf16(am0, *(const bf8*)(t0 + lane*8), gi_r, 0,0,0);
    gi_r = __builtin_amdgcn_mfma_f32_16x16x32_bf16(am1, *(const bf8*)(t0 + 512 + lane*8), gi_r, 0,0,0);
    gi_z = __builtin_amdgcn_mfma_f32_16x16x32_bf16(am0, *(const bf8*)(t1 + lane*8), gi_z, 0,0,0);
    gi_z = __builtin_amdgcn_mfma_f32_16x16x32_bf16(am1, *(const bf8*)(t1 + 512 + lane*8), gi_z, 0,0,0);
    gi_n = __builtin_amdgcn_mfma_f32_16x16x32_bf16(am0, *(const bf8*)(t2 + lane*8), gi_n, 0,0,0);
    gi_n = __builtin_amdgcn_mfma_f32_16x16x32_bf16(am1, *(const bf8*)(t2 + 512 + lane*8), gi_n, 0,0,0);
    gh_r = __builtin_amdgcn_mfma_f32_16x16x32_bf16(af0, *(const bf8*)(u0 + lane*8), gh_r, 0,0,0);
    gh_r = __builtin_amdgcn_mfma_f32_16x16x32_bf16(af1, *(const bf8*)(u0 + 512 + lane*8), gh_r, 0,0,0);
    gh_z = __builtin_amdgcn_mfma_f32_16x16x32_bf16(af0, *(const bf8*)(u1 + lane*8), gh_z, 0,0,0);
    gh_z = __builtin_amdgcn_mfma_f32_16x16x32_bf16(af1, *(const bf8*)(u1 + 512 + lane*8), gh_z, 0,0,0);
    gh_n = __builtin_amdgcn_mfma_f32_16x16x32_bf16(af0, *(const bf8*)(u2 + lane*8), gh_n, 0,0,0);
    gh_n = __builtin_amdgcn_mfma_f32_16x16x32_bf16(af1, *(const bf8*)(u2 + 512 + lane*8), gh_n, 0,0,0);
  }
  float bi0 = bih[o], bi1 = bih[64+o], bi2 = bih[128+o];
  float bh0 = bhh[o], bh1 = bhh[64+o], bh2 = bhh[128+o];
  #pragma unroll
  for (int j=0; j<4; ++j){
    int node = n0 + kg*4 + j;
    if (node < NN){
      size_t idx = (size_t)node*DD + o;
      float hv = h[idx];
      float r = sg(gi_r[j] + bi0 + gh_r[j] + bh0);
      float z = sg(gi_z[j] + bi1 + gh_z[j] + bh1);
      float nn = tanhf(gi_n[j] + bi2 + r*(gh_n[j] + bh2));
      float nh = (1.f - z)*nn + z*hv;
      h[idx] = nh;
      hbf[idx] = f2bf(nh);
    }
  }
}

// ---------- heads ----------
__global__ __launch_bounds__(256) void k_jbond(const float* __restrict__ h, const int* __restrict__ idx,
                        const float* __restrict__ w1T, const float* __restrict__ b1,
                        const float* __restrict__ w2, const float* __restrict__ b2,
                        float* __restrict__ jtmp){
  int wid = (blockIdx.x*blockDim.x + threadIdx.x) >> 6;
  int lane = threadIdx.x & 63;
  if (wid >= NJ*2) return;
  int a = idx[wid];
  float f = h[(size_t)a*DD + lane];
  float acc = b1[lane];
  for (int i=0; i<DD; ++i) acc += __shfl(f, i) * w1T[i*DD + lane];
  float p = lk(acc) * w2[lane];
  #pragma unroll
  for (int off=32; off; off>>=1) p += __shfl_xor(p, off);
  if (lane == 0) jtmp[wid] = p + b2[0];
}
__global__ __launch_bounds__(256) void k_jmean(const float* __restrict__ jtmp, float* __restrict__ o){
  int j = blockIdx.x*blockDim.x + threadIdx.x;
  if (j < NJ) o[j] = 0.5f*(jtmp[2*j] + jtmp[2*j+1]);
}
__global__ __launch_bounds__(256) void k_stem1(const float* __restrict__ h, const int* __restrict__ idx,
                        const float* __restrict__ w1T, const float* __restrict__ b1,
                        float* __restrict__ st1){
  int wid = (blockIdx.x*blockDim.x + threadIdx.x) >> 6;
  int lane = threadIdx.x & 63;
  if (wid >= NS) return;
  int a = idx[wid];
  float f = h[(size_t)a*DD + lane];
  float acc = b1[lane];
  for (int i=0; i<DD; ++i) acc += __shfl(f, i) * w1T[i*DD + lane];
  st1[(size_t)wid*DD + lane] = lk(acc);
}
// w2T[k*NO + c] layout -> coalesced inner loop
__global__ __launch_bounds__(256) void k_stem2(const float* __restrict__ st1, const float* __restrict__ w2T,
                        const float* __restrict__ b2, float* __restrict__ o){
  int i = blockIdx.x*blockDim.x + threadIdx.x;
  if (i >= NS*NO) return;
  int r = i / NO, c = i - r*NO;
  float acc = b2[c];
  const float* t1 = st1 + (size_t)r*DD;
  for (int k=0; k<DD; ++k) acc += t1[k]*w2T[k*NO + c];
  o[i] = acc;
}

// ---------- Set2Set (1 step, zero init state) ----------
__global__ void k_qvec(const float* __restrict__ bih, const float* __restrict__ bhh, float* __restrict__ qv){
  int g = threadIdx.x;
  float gi = bih[g] + bhh[g];
  float gg = bih[128+g] + bhh[128+g];
  float go = bih[192+g] + bhh[192+g];
  float c = sg(gi)*tanhf(gg);
  qv[g] = sg(go)*tanhf(c);
}
__global__ __launch_bounds__(256) void k_e(const float* __restrict__ h, const float* __restrict__ qv,
                    const int* __restrict__ batch, float* __restrict__ evec, unsigned* __restrict__ emax){
  int n = (blockIdx.x*blockDim.x + threadIdx.x) >> 6;
  int lane = threadIdx.x & 63;
  if (n >= NN) return;
  float p = h[(size_t)n*DD + lane] * qv[lane];
  #pragma unroll
  for (int off=32; off; off>>=1) p += __shfl_xor(p, off);
  if (lane == 0){
    evec[n] = p;
    atomicMax(&emax[batch[n]], fenc(p));
  }
}
// wave per graph: rvec[g] = sum(ex_n * h_n) / sum(ex_n), single pass over batch-CSR
__global__ __launch_bounds__(256) void k_gsum(const float* __restrict__ h, const float* __restrict__ evec,
                       const unsigned* __restrict__ emax, const int* __restrict__ gptr,
                       float* __restrict__ rvec){
  int g = (blockIdx.x*blockDim.x + threadIdx.x) >> 6;
  int lane = threadIdx.x & 63;
  if (g >= NGG) return;
  int a = gptr[g], b = gptr[g+1];
  if (a >= b){ rvec[(size_t)g*DD + lane] = 0.f; return; }
  float m = fdec(emax[g]);
  float s = 0.f, vacc = 0.f;
  for (int n=a; n<b; ++n){
    float ex = expf(evec[n] - m);
    s += ex;
    vacc += ex * h[(size_t)n*DD + lane];
  }
  rvec[(size_t)g*DD + lane] = vacc / s;
}
__global__ __launch_bounds__(256) void k_gout(const float* __restrict__ qv, const float* __restrict__ rvec,
                       const float* __restrict__ lw, const float* __restrict__ lb, float* __restrict__ o){
  int t = blockIdx.x*blockDim.x + threadIdx.x;
  if (t >= NGG*2) return;
  int g = t >> 1, c = t & 1;
  float acc = lb[c];
  for (int j=0; j<DD; ++j) acc += qv[j]*lw[c*128 + j];
  for (int j=0; j<DD; ++j) acc += rvec[(size_t)g*DD + j]*lw[c*128 + 64 + j];
  o[g*2 + c] = acc;
}

// ---------- host ----------
extern "C" void kernel_launch(void* const* d_in, const int* in_sizes, int n_in,
                              void* d_out_, int out_size, void* d_ws, size_t ws_size,
                              hipStream_t stream){
  const float* x        = (const float*)d_in[0];
  const int*   ei       = (const int*)d_in[1];
  const float* eattr    = (const float*)d_in[2];
  const int*   jbidx    = (const int*)d_in[3];
  const int*   stidx    = (const int*)d_in[4];
  const int*   batch    = (const int*)d_in[5];
  const float* lin0_w   = (const float*)d_in[6];
  const float* lin0_b   = (const float*)d_in[7];
  const float* net1_w   = (const float*)d_in[8];
  const float* net1_b   = (const float*)d_in[9];
  const float* net2_w   = (const float*)d_in[10];
  const float* net2_b   = (const float*)d_in[11];
  const float* conv_root= (const float*)d_in[12];
  const float* conv_b   = (const float*)d_in[13];
  const float* gru_wih  = (const float*)d_in[14];
  const float* gru_whh  = (const float*)d_in[15];
  const float* gru_bih  = (const float*)d_in[16];
  const float* gru_bhh  = (const float*)d_in[17];
  const float* n2s_w1   = (const float*)d_in[18];
  const float* n2s_b1   = (const float*)d_in[19];
  const float* n2s_w2   = (const float*)d_in[20];
  const float* n2s_b2   = (const float*)d_in[21];
  const float* n2j_w1   = (const float*)d_in[22];
  const float* n2j_b1   = (const float*)d_in[23];
  const float* n2j_w2   = (const float*)d_in[24];
  const float* n2j_b2   = (const float*)d_in[25];
  const float* lstm_bih = (const float*)d_in[28];
  const float* lstm_bhh = (const float*)d_in[29];
  const float* lout_w   = (const float*)d_in[30];
  const float* lout_b   = (const float*)d_in[31];
  float* out = (float*)d_out_;

  const int* src = ei;
  const int* dst = ei + NE;

  char* ws = (char*)d_ws;
  size_t off = 0;
  auto alloc = [&](size_t bytes)->void*{
    void* p = ws + off; off = (off + bytes + 255) & ~(size_t)255; return p;
  };
  float* h    = (float*)alloc((size_t)NN*DD*4);
  float* msgbuf = (float*)alloc((size_t)NE*DD*4);
  unsigned short* hbf = (unsigned short*)alloc((size_t)NPAD*DD*2);
  unsigned short* e1s = (unsigned short*)alloc((size_t)NE*DD*2);
  unsigned short* w2t = (unsigned short*)alloc((size_t)W2T_ELEMS*2);
  unsigned short* wgru = (unsigned short*)alloc((size_t)WG_ELEMS*2);
  // ---- zeroed group (one memset) ----
  int* degS   = (int*)alloc((size_t)NPAD*4);
  int* cnt    = (int*)alloc((size_t)NPAD*4);
  int* degD   = (int*)alloc((size_t)NPAD*4);
  int* cntD   = (int*)alloc((size_t)NPAD*4);
  int* ghist  = (int*)alloc((size_t)NGG*4);
  unsigned* emax = (unsigned*)alloc((size_t)NGG*4);   // end of zeroed group
  char* zend = ws + off;
  // ---- rest ----
  int* rowptr  = (int*)alloc((size_t)(NPAD+1)*4);
  int* rowptrD = (int*)alloc((size_t)(NPAD+1)*4);
  int* gptr    = (int*)alloc((size_t)(NGG+1)*4);
  int* sEid   = (int*)alloc((size_t)NE*4);
  int* sDpos  = (int*)alloc((size_t)NE*4);
  float* invd = (float*)alloc((size_t)NN*4);
  float* w1jT = (float*)alloc((size_t)DD*DD*4);
  float* w1sT = (float*)alloc((size_t)DD*DD*4);
  float* w2sT = (float*)alloc((size_t)DD*NO*4);
  float* evec = (float*)alloc((size_t)NN*4);
  float* rvec  = (float*)alloc((size_t)NGG*DD*4);
  float* qv    = (float*)alloc((size_t)DD*4);
  float* jtmp  = (float*)alloc((size_t)NJ*2*4);
  float* st1   = (float*)alloc((size_t)NS*DD*4);

  hipFuncSetAttribute((const void*)k_fused8, hipFuncAttributeMaxDynamicSharedMemorySize, LDSB);

  // ---- setup ----
  hipMemsetAsync(degS, 0, (size_t)(zend - (char*)degS), stream);  // degS,cnt,degD,cntD,ghist,emax
  k_lin0<<<(NPAD+3)/4, 256, 0, stream>>>(x, lin0_w, lin0_b, h, hbf);
  k_w2t<<<(W2T_ELEMS+255)/256, 256, 0, stream>>>(net2_w, net2_b, w2t);
  k_wg<<<(WG_ELEMS+255)/256, 256, 0, stream>>>(conv_root, gru_wih, gru_whh, wgru);
  k_tr<<<16, 256, 0, stream>>>(n2j_w1, w1jT, 64, 64);
  k_tr<<<16, 256, 0, stream>>>(n2s_w1, w1sT, 64, 64);
  k_tr<<<27, 256, 0, stream>>>(n2s_w2, w2sT, NO, DD);
  // edge sorts (src-CSR and dst-CSR) + batch-CSR
  k_hist<<<391, 256, 0, stream>>>(src, dst, degS, degD);
  k_invd<<<98, 256, 0, stream>>>(degD, invd);
  k_scan<<<1, 1024, 0, stream>>>(degS, rowptr);
  k_scan<<<1, 1024, 0, stream>>>(degD, rowptrD);
  k_scatter<<<391, 256, 0, stream>>>(src, dst, rowptr, cnt, rowptrD, cntD, sEid, sDpos);
  k_e1s<<<25000, 256, 0, stream>>>(eattr, net1_w, net1_b, sEid, e1s);
  k_ghist<<<98, 256, 0, stream>>>(batch, ghist);
  k_gscan<<<1, 512, 0, stream>>>(ghist, gptr);

  // ---- 6 message-passing + GRU iterations (atomic-free) ----
  for (int it=0; it<6; ++it){
    k_fused8<<<TOTBLK, 512, LDSB, stream>>>(w2t, hbf, e1s, sDpos, rowptr, msgbuf);
    k_gru<<<NBLK, 256, 0, stream>>>(h, hbf, msgbuf, rowptrD, invd, wgru, conv_b, gru_bih, gru_bhh);
  }

  // ---- heads ----
  k_jbond<<<512, 256, 0, stream>>>(h, jbidx, w1jT, n2j_b1, n2j_w2, n2j_b2, jtmp);
  k_jmean<<<4, 256, 0, stream>>>(jtmp, out + NGG*2 + NS*NO);
  k_stem1<<<512, 256, 0, stream>>>(h, stidx, w1sT, n2s_b1, st1);
  k_stem2<<<840, 256, 0, stream>>>(st1, w2sT, n2s_b2, out + NGG*2);

  // ---- Set2Set ----
  k_qvec<<<1, 64, 0, stream>>>(lstm_bih, lstm_bhh, qv);
  k_e<<<6250, 256, 0, stream>>>(h, qv, batch, evec, emax);
  k_gsum<<<128, 256, 0, stream>>>(h, evec, emax, gptr, rvec);
  k_gout<<<4, 256, 0, stream>>>(qv, rvec, lout_w, lout_b, out);
}